// Round 5
// baseline (445.703 us; speedup 1.0000x reference)
//
#include <hip/hip_runtime.h>
#include <hip/hip_fp16.h>

constexpr int NN   = 131072;   // total nodes
constexpr int PP   = 4096;     // nodes per graph
constexpr int BG   = 32;       // graphs
constexpr int EE   = 2097152;  // edges
constexpr int IND  = 64;
constexpr int HH   = 128;
constexpr int CAP  = 69632;    // per-graph edge slot capacity (mean 65536, +16 sigma)
constexpr float EPSV   = 1e-5f;
constexpr float SLOPEV = 0.01f;

typedef short bf16x8 __attribute__((ext_vector_type(8)));
typedef float f32x4  __attribute__((ext_vector_type(4)));

__device__ __forceinline__ unsigned f2bf(float f) {
    unsigned u = __float_as_uint(f);
    return (u + 0x7FFFu + ((u >> 16) & 1u)) >> 16;      // RNE
}
__device__ __forceinline__ unsigned pack2bf(float lo, float hi) {
    return f2bf(lo) | (f2bf(hi) << 16);
}
__device__ __forceinline__ float bflo(unsigned p) { return __uint_as_float(p << 16); }
__device__ __forceinline__ float bfhi(unsigned p) { return __uint_as_float(p & 0xFFFF0000u); }
__device__ __forceinline__ float w16(unsigned r) {
    return __half2float(__ushort_as_half((unsigned short)(r >> 16)));
}

// ---------------- W -> MFMA B-fragment prepack (device body) ----------------
template <int K>
__device__ __forceinline__ void packw_body(const float* __restrict__ W,
                                           unsigned short* __restrict__ pw, int t) {
    if (t >= K * 16) return;
    int lane = t & 63, nt = (t >> 6) & 7, kt = t >> 9;
    int kbase = kt * 32 + ((lane >> 4) & 3) * 8;
    int col   = nt * 16 + (lane & 15);
    for (int j = 0; j < 8; j++)
        pw[t * 8 + j] = (unsigned short)f2bf(W[(kbase + j) * HH + col]);
}

// ---------------- fused prep: feature cvt + init + weight prepack ----------------
__global__ __launch_bounds__(256) void k_prep(const float* __restrict__ features,
                                              unsigned* __restrict__ fx,
                                              const float* __restrict__ W1,
                                              unsigned short* __restrict__ pw1,
                                              const float* __restrict__ W2,
                                              unsigned short* __restrict__ pw2,
                                              int* __restrict__ gcur,
                                              float* __restrict__ racc) {
    int b = blockIdx.x, t = threadIdx.x;
    if (b < 16384) {                    // bf16 convert: NN*IND/2 = 16384*256 words
        int i = b * 256 + t;
        float2 v = ((const float2*)features)[i];
        fx[i] = pack2bf(v.x, v.y);
        return;
    }
    if (b == 16384) {                   // init cursors + readout accumulators
        if (t < BG) gcur[t * 16] = t * CAP;
        for (int i = t; i < 2 * BG * HH; i += 256) racc[i] = 0.f;
        return;
    }
    if (b < 16389) { packw_body<64>(W1, pw1, (b - 16385) * 256 + t); return; }
    packw_body<128>(W2, pw2, (b - 16389) * 256 + t);
}

// ---------------- pass 1: 32-way partition of edges by graph ----------------
__global__ __launch_bounds__(256) void k_part(const int* __restrict__ src,
                                              const int* __restrict__ dst,
                                              const float* __restrict__ ew,
                                              int* __restrict__ gcur,
                                              uint2* __restrict__ recs) {
    __shared__ int cnt[32];
    __shared__ int start[32];
    __shared__ int gbase[32];
    __shared__ uint2 stage[4096];
    int t = threadIdx.x;
    int ebase = blockIdx.x * 4096;
    if (t < 32) cnt[t] = 0;
    __syncthreads();
    int es[16]; int ed[16]; float ev[16];
#pragma unroll
    for (int k = 0; k < 16; k++) {
        int e = ebase + k * 256 + t;
        es[k] = src[e]; ed[k] = dst[e]; ev[k] = ew[e];
        atomicAdd(&cnt[es[k] >> 12], 1);
    }
    __syncthreads();
    if (t == 0) {
        int run = 0;
        for (int g = 0; g < 32; g++) { start[g] = run; run += cnt[g]; }
    }
    __syncthreads();
    if (t < 32) {
        gbase[t] = atomicAdd(&gcur[t * 16], cnt[t]);
        cnt[t] = start[t];                      // becomes cursor
    }
    __syncthreads();
#pragma unroll
    for (int k = 0; k < 16; k++) {
        int g = es[k] >> 12;
        int pos = atomicAdd(&cnt[g], 1);
        stage[pos] = make_uint2((unsigned)(es[k] & 4095) | ((unsigned)(ed[k] & 4095) << 12) |
                                ((unsigned)g << 24), __float_as_uint(ev[k]));
    }
    __syncthreads();
    for (int i = t; i < 4096; i += 256) {
        uint2 r = stage[i];
        int g = r.x >> 24;
        recs[gbase[g] + (i - start[g])] = r;
    }
}

// ---------------- build phase A: per-(graph,chunk) histograms ----------------
__global__ __launch_bounds__(1024) void k_hist(const uint2* __restrict__ recs,
                                               const int* __restrict__ gcur,
                                               int* __restrict__ shist,
                                               int* __restrict__ dhist) {
    __shared__ int hs[4096];
    __shared__ int hd[4096];
    int t = threadIdx.x;
    int g = blockIdx.x >> 3, c = blockIdx.x & 7;
    int n = gcur[g * 16] - g * CAP;
    int lo = (n * c) >> 3, hi = (n * (c + 1)) >> 3;
    ((int4*)hs)[t] = make_int4(0, 0, 0, 0);
    ((int4*)hd)[t] = make_int4(0, 0, 0, 0);
    __syncthreads();
    const uint2* base = recs + (size_t)g * CAP;
    for (int i = lo + t; i < hi; i += 1024) {
        unsigned x = base[i].x;
        atomicAdd(&hs[x & 4095], 1);
        atomicAdd(&hd[(x >> 12) & 4095], 1);
    }
    __syncthreads();
    ((int4*)(shist + (size_t)blockIdx.x * 4096))[t] = ((int4*)hs)[t];
    ((int4*)(dhist + (size_t)blockIdx.x * 4096))[t] = ((int4*)hd)[t];
}

// ---------------- build phase B: degrees, rsqrt, offsets, chunk cursor bases ----------------
__global__ __launch_bounds__(1024) void k_offs(int* __restrict__ shist,
                                               int* __restrict__ dhist,
                                               float* __restrict__ rs_s,
                                               float* __restrict__ rsd,
                                               int* __restrict__ degd,
                                               int* __restrict__ offs) {
    __shared__ int partial[1024];
    int t = threadIdx.x, g = blockIdx.x;
    int sdeg[4] = {0, 0, 0, 0}, ddeg[4] = {0, 0, 0, 0};
#pragma unroll
    for (int c = 0; c < 8; c++) {
        int4 sv = ((const int4*)(shist + (size_t)(g * 8 + c) * 4096))[t];
        int4 dv = ((const int4*)(dhist + (size_t)(g * 8 + c) * 4096))[t];
        sdeg[0] += sv.x; sdeg[1] += sv.y; sdeg[2] += sv.z; sdeg[3] += sv.w;
        ddeg[0] += dv.x; ddeg[1] += dv.y; ddeg[2] += dv.z; ddeg[3] += dv.w;
    }
#pragma unroll
    for (int j = 0; j < 4; j++) {
        int idx = t * 4 + j;
        int vs = sdeg[j]; if (vs < 1) vs = 1;
        rs_s[g * PP + idx] = rsqrtf((float)vs);
        int vd = ddeg[j]; if (vd < 1) vd = 1;
        rsd[g * PP + idx]  = rsqrtf((float)vd);
        degd[g * PP + idx] = ddeg[j];
    }
    partial[t] = ddeg[0] + ddeg[1] + ddeg[2] + ddeg[3];
    __syncthreads();
    for (int off = 1; off < 1024; off <<= 1) {
        int v = partial[t];
        int add = (t >= off) ? partial[t - off] : 0;
        __syncthreads();
        partial[t] = v + add;
        __syncthreads();
    }
    int run = (t == 0) ? 0 : partial[t - 1];
#pragma unroll
    for (int j = 0; j < 4; j++) {
        int idx = t * 4 + j;
        offs[g * PP + idx] = g * CAP + run;
        int nb = run;
        for (int c = 0; c < 8; c++) {
            size_t hidx = (size_t)(g * 8 + c) * 4096 + idx;
            int v = dhist[hidx];
            dhist[hidx] = nb;                 // per-chunk cursor base (graph-relative)
            nb += v;
        }
        run = nb;
    }
}

// ---------------- build phase C: counting-sort placement ----------------
__global__ __launch_bounds__(1024) void k_place(const uint2* __restrict__ recs,
                                                const int* __restrict__ gcur,
                                                const int* __restrict__ dhist,
                                                const float* __restrict__ rs_s,
                                                unsigned* __restrict__ csr2) {
    __shared__ int cur[4096];
    __shared__ float rss[4096];
    int t = threadIdx.x;
    int g = blockIdx.x >> 3, c = blockIdx.x & 7;
    int n = gcur[g * 16] - g * CAP;
    int lo = (n * c) >> 3, hi = (n * (c + 1)) >> 3;
    ((int4*)cur)[t] = ((const int4*)(dhist + (size_t)blockIdx.x * 4096))[t];
    ((float4*)rss)[t] = ((const float4*)(rs_s + (size_t)g * PP))[t];
    __syncthreads();
    const uint2* base = recs + (size_t)g * CAP;
    unsigned* cbase = csr2 + (size_t)g * CAP;
    for (int i = lo + t; i < hi; i += 1024) {
        uint2 r = base[i];
        int sl = r.x & 4095, dl = (r.x >> 12) & 4095;
        int pos = atomicAdd(&cur[dl], 1);
        float wf = __uint_as_float(r.y) * rss[sl];
        cbase[pos] = (unsigned)sl | ((unsigned)__half_as_ushort(__float2half(wf)) << 16);
    }
}

// ---------------- agg layer 1: wave per node, quarter-wave per edge, 8B gathers ----------------
__global__ __launch_bounds__(256) void k_agg1(const unsigned* __restrict__ fx,   // [NN*32]
                                              const unsigned* __restrict__ csr2,
                                              const int* __restrict__ offs,
                                              const int* __restrict__ degd,
                                              const float* __restrict__ rsd,
                                              unsigned* __restrict__ m1) {      // [NN*32]
    int bid = blockIdx.x;                       // NN/4 blocks
    int xcd = bid & 7, idx = bid >> 3;
    int g = xcd * 4 + (idx >> 10);
    int node0 = g * PP + (idx & 1023) * 4;
    int lane = threadIdx.x & 63, wv = threadIdx.x >> 6;
    int v = node0 + wv;
    int o = offs[v], cnt = degd[v];
    float rd = rsd[v];
    int qi = lane >> 4, ql = lane & 15;
    const unsigned* hp = fx + (size_t)((unsigned)(v & ~(PP - 1)) * 32) + ql * 2;
    float a0 = 0.f, a1 = 0.f, a2 = 0.f, a3 = 0.f;
    int i = 0;
    for (; i + 4 <= cnt; i += 4) {              // 4 edges per iter, one per quarter-wave
        unsigned r = csr2[o + i + qi];
        float w = w16(r);
        uint2 gg = *(const uint2*)(hp + (size_t)(r & 4095) * 32);
        a0 += w * bflo(gg.x); a1 += w * bfhi(gg.x);
        a2 += w * bflo(gg.y); a3 += w * bfhi(gg.y);
    }
    if (i < cnt) {                               // masked tail (up to 3 edges)
        int j = i + qi;
        bool valid = j < cnt;
        unsigned r = csr2[valid ? o + j : o + i];
        float w = valid ? w16(r) : 0.f;
        uint2 gg = *(const uint2*)(hp + (size_t)(r & 4095) * 32);
        a0 += w * bflo(gg.x); a1 += w * bfhi(gg.x);
        a2 += w * bflo(gg.y); a3 += w * bfhi(gg.y);
    }
    a0 += __shfl_xor(a0, 16, 64); a0 += __shfl_xor(a0, 32, 64);
    a1 += __shfl_xor(a1, 16, 64); a1 += __shfl_xor(a1, 32, 64);
    a2 += __shfl_xor(a2, 16, 64); a2 += __shfl_xor(a2, 32, 64);
    a3 += __shfl_xor(a3, 16, 64); a3 += __shfl_xor(a3, 32, 64);
    if (qi == 0) {
        uint2 ow;
        ow.x = pack2bf(a0 * rd, a1 * rd);
        ow.y = pack2bf(a2 * rd, a3 * rd);
        *(uint2*)(m1 + (size_t)v * 32 + ql * 2) = ow;
    }
}

// ---------------- agg layer 2: wave per node, half-wave per edge, 8B gathers ----------------
__global__ __launch_bounds__(256) void k_agg2(const unsigned* __restrict__ h1,   // [NN*64]
                                              const unsigned* __restrict__ csr2,
                                              const int* __restrict__ offs,
                                              const int* __restrict__ degd,
                                              const float* __restrict__ rsd,
                                              unsigned* __restrict__ m2) {       // [NN*64]
    int bid = blockIdx.x;                        // NN/4 blocks
    int xcd = bid & 7, idx = bid >> 3;
    int g = xcd * 4 + (idx >> 10);
    int node0 = g * PP + (idx & 1023) * 4;
    int lane = threadIdx.x & 63, wv = threadIdx.x >> 6;
    int v = node0 + wv;
    int o = offs[v], cnt = degd[v];
    float rd = rsd[v];
    int half = lane >> 5, hl = lane & 31;
    const unsigned* hp = h1 + (size_t)((unsigned)(v & ~(PP - 1)) * 64) + hl * 2;
    float a0 = 0.f, a1 = 0.f, a2 = 0.f, a3 = 0.f;
    float b0 = 0.f, b1 = 0.f, b2 = 0.f, b3 = 0.f;
    int i = 0;
    for (; i + 4 <= cnt; i += 4) {               // 4 edges per iter, 2 per half-wave
        uint2 rr = *(const uint2*)(csr2 + o + i + half * 2);
        float wa = w16(rr.x), wb = w16(rr.y);
        uint2 ga = *(const uint2*)(hp + (size_t)(rr.x & 4095) * 64);
        uint2 gb = *(const uint2*)(hp + (size_t)(rr.y & 4095) * 64);
        a0 += wa * bflo(ga.x); a1 += wa * bfhi(ga.x);
        a2 += wa * bflo(ga.y); a3 += wa * bfhi(ga.y);
        b0 += wb * bflo(gb.x); b1 += wb * bfhi(gb.x);
        b2 += wb * bflo(gb.y); b3 += wb * bfhi(gb.y);
    }
    if (i < cnt) {                               // masked tail (up to 3 edges)
        int j = i + half;
        bool v1 = j < cnt;
        unsigned ra = csr2[v1 ? o + j : o + i];
        float wa = v1 ? w16(ra) : 0.f;
        uint2 ga = *(const uint2*)(hp + (size_t)(ra & 4095) * 64);
        a0 += wa * bflo(ga.x); a1 += wa * bfhi(ga.x);
        a2 += wa * bflo(ga.y); a3 += wa * bfhi(ga.y);
        int j2 = j + 2;
        bool v2 = j2 < cnt;
        unsigned rb = csr2[v2 ? o + j2 : o + i];
        float wb = v2 ? w16(rb) : 0.f;
        uint2 gb = *(const uint2*)(hp + (size_t)(rb & 4095) * 64);
        b0 += wb * bflo(gb.x); b1 += wb * bfhi(gb.x);
        b2 += wb * bflo(gb.y); b3 += wb * bfhi(gb.y);
    }
    a0 += b0; a1 += b1; a2 += b2; a3 += b3;
    a0 += __shfl_xor(a0, 32, 64);
    a1 += __shfl_xor(a1, 32, 64);
    a2 += __shfl_xor(a2, 32, 64);
    a3 += __shfl_xor(a3, 32, 64);
    if (half == 0) {
        uint2 ow;
        ow.x = pack2bf(a0 * rd, a1 * rd);
        ow.y = pack2bf(a2 * rd, a3 * rd);
        *(uint2*)(m2 + (size_t)v * 64 + hl * 2) = ow;
    }
}

// ---------------- MFMA GEMM (bf16 out) + fused column-stat partials ----------------
template <int K>
__global__ __launch_bounds__(256) void k_gemm(const short* __restrict__ A,
                                              const short* __restrict__ PW,
                                              unsigned short* __restrict__ C,   // bf16 out
                                              float* __restrict__ part) {
    __shared__ float s1[HH], s2[HH];
    int t = threadIdx.x;
    if (t < HH) { s1[t] = 0.f; s2[t] = 0.f; }
    __syncthreads();
    int wv = t >> 6, lane = t & 63;
    int tile = blockIdx.x * 4 + wv;              // 16-row tile; grid = NN/64
    int m = lane & 15, quad = lane >> 4;
    int row = tile * 16 + m;
    bf16x8 a[K / 32];
#pragma unroll
    for (int kt = 0; kt < K / 32; kt++)
        a[kt] = *(const bf16x8*)(A + (size_t)row * K + kt * 32 + quad * 8);
#pragma unroll
    for (int nt = 0; nt < 8; nt++) {
        f32x4 acc = {0.f, 0.f, 0.f, 0.f};
#pragma unroll
        for (int kt = 0; kt < K / 32; kt++) {
            bf16x8 b = *(const bf16x8*)(PW + ((size_t)(kt * 8 + nt) * 64 + lane) * 8);
            acc = __builtin_amdgcn_mfma_f32_16x16x32_bf16(a[kt], b, acc, 0, 0, 0);
        }
        int col = nt * 16 + m;
        int r0 = tile * 16 + quad * 4;
        float ps = 0.f, pq = 0.f;
#pragma unroll
        for (int r = 0; r < 4; r++) {
            C[(size_t)(r0 + r) * HH + col] = (unsigned short)f2bf(acc[r]);
            ps += acc[r]; pq += acc[r] * acc[r];
        }
        atomicAdd(&s1[col], ps);
        atomicAdd(&s2[col], pq);
    }
    __syncthreads();
    if (t < HH) {
        part[blockIdx.x * 256 + t]      = s1[t];
        part[blockIdx.x * 256 + HH + t] = s2[t];
    }
}

// ---------------- stage-1 reduction of gemm partials ----------------
__global__ __launch_bounds__(256) void k_red(const float* __restrict__ part,
                                             float* __restrict__ pb) {
    int t = threadIdx.x, b = blockIdx.x;        // 64 blocks
    float s = 0.f;
    for (int r = 0; r < 32; r++) s += part[(size_t)(b * 32 + r) * 256 + t];
    pb[b * 256 + t] = s;
}

// ---------------- reduce + norm coefficients ----------------
__global__ void k_coef(const float* __restrict__ pb, const float* __restrict__ gamma,
                       const float* __restrict__ beta, const float* __restrict__ alpha,
                       float* __restrict__ ab) {
    int t = threadIdx.x;                         // 256 threads
    float s = 0.f;
    for (int b = 0; b < 64; b++) s += pb[b * 256 + t];
    __shared__ float sh[256];
    sh[t] = s;
    __syncthreads();
    if (t < 128) {
        float mu = sh[t] * (1.f / NN);
        float e2 = sh[128 + t] * (1.f / NN);
        float al = alpha[t];
        float var = e2 - (2.f * al - al * al) * mu * mu;
        float a = rsqrtf(var + EPSV) * gamma[t];
        ab[t] = a;
        ab[HH + t] = beta[t] - al * mu * a;
    }
}

// ---------------- fused norm + leaky-relu (in-place bf16) + per-graph readout ----------------
template <bool WRITE>
__global__ __launch_bounds__(256) void k_normro(unsigned* __restrict__ h,       // bf16 pairs
                                                const float* __restrict__ ab,
                                                float* __restrict__ racc) {
    int fp = threadIdx.x & 63;                   // feature pair
    int q  = threadIdx.x >> 6;                   // 0..3
    int node0 = blockIdx.x * 64;                 // one graph per block
    int g = node0 / PP;
    float a0 = ab[2 * fp], a1 = ab[2 * fp + 1];
    float b0 = ab[HH + 2 * fp], b1 = ab[HH + 2 * fp + 1];
    float s0 = 0.f, s1 = 0.f;
    for (int i = q; i < 64; i += 4) {
        size_t idx = (size_t)(node0 + i) * 64 + fp;
        unsigned v = h[idx];
        float x0 = fmaf(a0, bflo(v), b0); x0 = x0 > 0.f ? x0 : SLOPEV * x0;
        float x1 = fmaf(a1, bfhi(v), b1); x1 = x1 > 0.f ? x1 : SLOPEV * x1;
        if (WRITE) h[idx] = pack2bf(x0, x1);
        s0 += x0; s1 += x1;
    }
    __shared__ float sh[512];
    sh[threadIdx.x] = s0;
    sh[256 + threadIdx.x] = s1;
    __syncthreads();
    if (q == 0) {
        float t0 = s0 + sh[64 + fp] + sh[128 + fp] + sh[192 + fp];
        float t1 = s1 + sh[256 + 64 + fp] + sh[256 + 128 + fp] + sh[256 + 192 + fp];
        atomicAdd(&racc[g * HH + 2 * fp],     t0);
        atomicAdd(&racc[g * HH + 2 * fp + 1], t1);
    }
}

// ---------------- final head ----------------
__global__ void k_final(const float* __restrict__ racc1, const float* __restrict__ racc2,
                        const float* __restrict__ Wc, float* __restrict__ out) {
    int t = threadIdx.x;                         // 512 = 32*16
    int b = t >> 4, o = t & 15;
    float acc = 0.f;
    for (int f = 0; f < HH; f++) acc += racc1[b * HH + f] * Wc[o * (2 * HH) + f];
    for (int f = 0; f < HH; f++) acc += racc2[b * HH + f] * Wc[o * (2 * HH) + HH + f];
    out[t] = acc * (1.f / PP);
}

extern "C" void kernel_launch(void* const* d_in, const int* in_sizes, int n_in,
                              void* d_out, int out_size, void* d_ws, size_t ws_size,
                              hipStream_t stream) {
    const float* features = (const float*)d_in[0];
    const float* ew       = (const float*)d_in[1];
    const int*   src      = (const int*)d_in[2];
    const int*   dst      = (const int*)d_in[3];
    const float* W1       = (const float*)d_in[4];
    const float* W2       = (const float*)d_in[5];
    const float* Wc       = (const float*)d_in[6];
    const float* gamma1   = (const float*)d_in[7];
    const float* beta1    = (const float*)d_in[8];
    const float* alpha1   = (const float*)d_in[9];
    const float* gamma2   = (const float*)d_in[10];
    const float* beta2    = (const float*)d_in[11];
    const float* alpha2   = (const float*)d_in[12];
    float* out = (float*)d_out;

    char* w = (char*)d_ws;
    // misc block [0, 1 MB)
    int*    gcur   = (int*)(w + 0);                         // 32 * 16 ints
    float*  racc1  = (float*)(w + (16u << 10));             // 16 KB
    float*  racc2  = (float*)(w + (32u << 10));             // contiguous with racc1
    float*  ab1    = (float*)(w + (48u << 10));
    float*  ab2    = (float*)(w + (52u << 10));
    unsigned short* pw1 = (unsigned short*)(w + (64u << 10));   // 16 KB
    unsigned short* pw2 = (unsigned short*)(w + (80u << 10));   // 32 KB
    float*  pb     = (float*)(w + (128u << 10));            // 64 KB
    // arrays
    float*  rs_s   = (float*)(w + (1024u << 10));           // 512 KB
    float*  rsd    = (float*)(w + (1536u << 10));           // 512 KB
    int*    degd   = (int*)(w + (2048u << 10));             // 512 KB
    int*    offs   = (int*)(w + (2560u << 10));             // 512 KB
    float*  part   = (float*)(w + (3u << 20));              // 2 MB: 3..5
    int*    shist  = (int*)(w + (5u << 20));                // 4 MB: 5..9
    int*    dhist  = (int*)(w + (9u << 20));                // 4 MB: 9..13
    unsigned* csr2 = (unsigned*)(w + (13u << 20));          // 8.5 MB: 13..21.5
    unsigned* mbuf = (unsigned*)(w + (22u << 20));          // 32 MB: 22..54
    unsigned* hbuf = (unsigned*)(w + (54u << 20));          // 32 MB: 54..86
    uint2*    recs = (uint2*)(w + (86u << 20));             // 17 MB: 86..103
    unsigned* fx   = (unsigned*)(w + (104u << 20));         // 16 MB: 104..120

    // prep (cvt + init + packw fused)
    k_prep<<<16397, 256, 0, stream>>>(features, fx, W1, pw1, W2, pw2, gcur, racc1);

    // CSR build
    k_part<<<EE / 4096, 256, 0, stream>>>(src, dst, ew, gcur, recs);
    k_hist<<<BG * 8, 1024, 0, stream>>>(recs, gcur, shist, dhist);
    k_offs<<<BG, 1024, 0, stream>>>(shist, dhist, rs_s, rsd, degd, offs);
    k_place<<<BG * 8, 1024, 0, stream>>>(recs, gcur, dhist, rs_s, csr2);

    // ---- layer 1 ----
    k_agg1<<<NN / 4, 256, 0, stream>>>(fx, csr2, offs, degd, rsd, mbuf);
    k_gemm<64><<<NN / 64, 256, 0, stream>>>((const short*)mbuf, (const short*)pw1,
                                            (unsigned short*)hbuf, part);
    k_red<<<64, 256, 0, stream>>>(part, pb);
    k_coef<<<1, 256, 0, stream>>>(pb, gamma1, beta1, alpha1, ab1);
    k_normro<true><<<NN / 64, 256, 0, stream>>>(hbuf, ab1, racc1);

    // ---- layer 2 ----
    k_agg2<<<NN / 4, 256, 0, stream>>>(hbuf, csr2, offs, degd, rsd, mbuf);
    k_gemm<128><<<NN / 64, 256, 0, stream>>>((const short*)mbuf, (const short*)pw2,
                                             (unsigned short*)hbuf, part);
    k_red<<<64, 256, 0, stream>>>(part, pb);
    k_coef<<<1, 256, 0, stream>>>(pb, gamma2, beta2, alpha2, ab2);
    k_normro<false><<<NN / 64, 256, 0, stream>>>(hbuf, ab2, racc2);

    // ---- head ----
    k_final<<<1, 512, 0, stream>>>(racc1, racc2, Wc, out);
}

// Round 6
// 412.797 us; speedup vs baseline: 1.0797x; 1.0797x over previous
//
#include <hip/hip_runtime.h>
#include <hip/hip_fp16.h>

constexpr int NN   = 131072;   // total nodes
constexpr int PP   = 4096;     // nodes per graph
constexpr int BG   = 32;       // graphs
constexpr int EE   = 2097152;  // edges
constexpr int IND  = 64;
constexpr int HH   = 128;
constexpr int CAP  = 81920;    // per-graph slot capacity (65536 mean + pad4 6144 + slack)
constexpr float EPSV   = 1e-5f;
constexpr float SLOPEV = 0.01f;

typedef short bf16x8 __attribute__((ext_vector_type(8)));
typedef float f32x4  __attribute__((ext_vector_type(4)));

__device__ __forceinline__ unsigned f2bf(float f) {
    unsigned u = __float_as_uint(f);
    return (u + 0x7FFFu + ((u >> 16) & 1u)) >> 16;      // RNE
}
__device__ __forceinline__ unsigned pack2bf(float lo, float hi) {
    return f2bf(lo) | (f2bf(hi) << 16);
}
__device__ __forceinline__ float bflo(unsigned p) { return __uint_as_float(p << 16); }
__device__ __forceinline__ float bfhi(unsigned p) { return __uint_as_float(p & 0xFFFF0000u); }
__device__ __forceinline__ float w16(unsigned r) {
    return __half2float(__ushort_as_half((unsigned short)(r >> 16)));
}

// ---------------- W -> MFMA B-fragment prepack (device body) ----------------
template <int K>
__device__ __forceinline__ void packw_body(const float* __restrict__ W,
                                           unsigned short* __restrict__ pw, int t) {
    if (t >= K * 16) return;
    int lane = t & 63, nt = (t >> 6) & 7, kt = t >> 9;
    int kbase = kt * 32 + ((lane >> 4) & 3) * 8;
    int col   = nt * 16 + (lane & 15);
    for (int j = 0; j < 8; j++)
        pw[t * 8 + j] = (unsigned short)f2bf(W[(kbase + j) * HH + col]);
}

// ---------------- fused prep: feature cvt + init + weight prepack ----------------
__global__ __launch_bounds__(256) void k_prep(const float* __restrict__ features,
                                              unsigned* __restrict__ fx,
                                              const float* __restrict__ W1,
                                              unsigned short* __restrict__ pw1,
                                              const float* __restrict__ W2,
                                              unsigned short* __restrict__ pw2,
                                              int* __restrict__ gcur,
                                              float* __restrict__ racc) {
    int b = blockIdx.x, t = threadIdx.x;
    if (b < 16384) {                    // bf16 convert: NN*IND/2 = 16384*256 words
        int i = b * 256 + t;
        float2 v = ((const float2*)features)[i];
        fx[i] = pack2bf(v.x, v.y);
        return;
    }
    if (b == 16384) {                   // init cursors + readout accumulators
        if (t < BG) gcur[t * 16] = t * CAP;
        for (int i = t; i < 2 * BG * HH; i += 256) racc[i] = 0.f;
        return;
    }
    if (b < 16389) { packw_body<64>(W1, pw1, (b - 16385) * 256 + t); return; }
    packw_body<128>(W2, pw2, (b - 16389) * 256 + t);
}

// ---------------- pass 1: 32-way partition of edges by graph ----------------
__global__ __launch_bounds__(256) void k_part(const int* __restrict__ src,
                                              const int* __restrict__ dst,
                                              const float* __restrict__ ew,
                                              int* __restrict__ gcur,
                                              uint2* __restrict__ recs) {
    __shared__ int cnt[32];
    __shared__ int start[32];
    __shared__ int gbase[32];
    __shared__ uint2 stage[4096];
    int t = threadIdx.x;
    int ebase = blockIdx.x * 4096;
    if (t < 32) cnt[t] = 0;
    __syncthreads();
    int es[16]; int ed[16]; float ev[16];
#pragma unroll
    for (int k = 0; k < 16; k++) {
        int e = ebase + k * 256 + t;
        es[k] = src[e]; ed[k] = dst[e]; ev[k] = ew[e];
        atomicAdd(&cnt[es[k] >> 12], 1);
    }
    __syncthreads();
    if (t == 0) {
        int run = 0;
        for (int g = 0; g < 32; g++) { start[g] = run; run += cnt[g]; }
    }
    __syncthreads();
    if (t < 32) {
        gbase[t] = atomicAdd(&gcur[t * 16], cnt[t]);
        cnt[t] = start[t];                      // becomes cursor
    }
    __syncthreads();
#pragma unroll
    for (int k = 0; k < 16; k++) {
        int g = es[k] >> 12;
        int pos = atomicAdd(&cnt[g], 1);
        stage[pos] = make_uint2((unsigned)(es[k] & 4095) | ((unsigned)(ed[k] & 4095) << 12) |
                                ((unsigned)g << 24), __float_as_uint(ev[k]));
    }
    __syncthreads();
    for (int i = t; i < 4096; i += 256) {
        uint2 r = stage[i];
        int g = r.x >> 24;
        recs[gbase[g] + (i - start[g])] = r;
    }
}

// ---------------- build phase A: per-(graph,chunk) histograms ----------------
__global__ __launch_bounds__(1024) void k_hist(const uint2* __restrict__ recs,
                                               const int* __restrict__ gcur,
                                               int* __restrict__ shist,
                                               int* __restrict__ dhist) {
    __shared__ int hs[4096];
    __shared__ int hd[4096];
    int t = threadIdx.x;
    int g = blockIdx.x >> 3, c = blockIdx.x & 7;
    int n = gcur[g * 16] - g * CAP;
    int lo = (n * c) >> 3, hi = (n * (c + 1)) >> 3;
    ((int4*)hs)[t] = make_int4(0, 0, 0, 0);
    ((int4*)hd)[t] = make_int4(0, 0, 0, 0);
    __syncthreads();
    const uint2* base = recs + (size_t)g * CAP;
    for (int i = lo + t; i < hi; i += 1024) {
        unsigned x = base[i].x;
        atomicAdd(&hs[x & 4095], 1);
        atomicAdd(&hd[(x >> 12) & 4095], 1);
    }
    __syncthreads();
    ((int4*)(shist + (size_t)blockIdx.x * 4096))[t] = ((int4*)hs)[t];
    ((int4*)(dhist + (size_t)blockIdx.x * 4096))[t] = ((int4*)hd)[t];
}

// ---------------- build phase B: degrees, rsqrt, padded offsets, chunk cursor bases ----------------
__global__ __launch_bounds__(1024) void k_offs(int* __restrict__ shist,
                                               int* __restrict__ dhist,
                                               float* __restrict__ rs_s,
                                               float* __restrict__ rsd,
                                               int* __restrict__ degd,
                                               int* __restrict__ offs) {
    __shared__ int partial[1024];
    int t = threadIdx.x, g = blockIdx.x;
    int sdeg[4] = {0, 0, 0, 0}, ddeg[4] = {0, 0, 0, 0};
#pragma unroll
    for (int c = 0; c < 8; c++) {
        int4 sv = ((const int4*)(shist + (size_t)(g * 8 + c) * 4096))[t];
        int4 dv = ((const int4*)(dhist + (size_t)(g * 8 + c) * 4096))[t];
        sdeg[0] += sv.x; sdeg[1] += sv.y; sdeg[2] += sv.z; sdeg[3] += sv.w;
        ddeg[0] += dv.x; ddeg[1] += dv.y; ddeg[2] += dv.z; ddeg[3] += dv.w;
    }
    int pdeg[4];
#pragma unroll
    for (int j = 0; j < 4; j++) {
        int idx = t * 4 + j;
        int vs = sdeg[j]; if (vs < 1) vs = 1;
        rs_s[g * PP + idx] = rsqrtf((float)vs);
        int vd = ddeg[j]; if (vd < 1) vd = 1;
        rsd[g * PP + idx]  = rsqrtf((float)vd);
        pdeg[j] = (ddeg[j] + 3) & ~3;           // padded to multiple of 4
        degd[g * PP + idx] = pdeg[j];           // agg loops run over padded count
    }
    partial[t] = pdeg[0] + pdeg[1] + pdeg[2] + pdeg[3];
    __syncthreads();
    for (int off = 1; off < 1024; off <<= 1) {
        int v = partial[t];
        int add = (t >= off) ? partial[t - off] : 0;
        __syncthreads();
        partial[t] = v + add;
        __syncthreads();
    }
    int run = (t == 0) ? 0 : partial[t - 1];
#pragma unroll
    for (int j = 0; j < 4; j++) {
        int idx = t * 4 + j;
        offs[g * PP + idx] = g * CAP + run;
        int nb = run;                           // true edges placed at segment start
        for (int c = 0; c < 8; c++) {
            size_t hidx = (size_t)(g * 8 + c) * 4096 + idx;
            int v = dhist[hidx];
            dhist[hidx] = nb;                   // per-chunk cursor base (graph-relative)
            nb += v;
        }
        run += pdeg[j];                         // pad region stays zero (memset)
    }
}

// ---------------- build phase C: counting-sort placement ----------------
__global__ __launch_bounds__(1024) void k_place(const uint2* __restrict__ recs,
                                                const int* __restrict__ gcur,
                                                const int* __restrict__ dhist,
                                                const float* __restrict__ rs_s,
                                                unsigned* __restrict__ csr2) {
    __shared__ int cur[4096];
    __shared__ float rss[4096];
    int t = threadIdx.x;
    int g = blockIdx.x >> 3, c = blockIdx.x & 7;
    int n = gcur[g * 16] - g * CAP;
    int lo = (n * c) >> 3, hi = (n * (c + 1)) >> 3;
    ((int4*)cur)[t] = ((const int4*)(dhist + (size_t)blockIdx.x * 4096))[t];
    ((float4*)rss)[t] = ((const float4*)(rs_s + (size_t)g * PP))[t];
    __syncthreads();
    const uint2* base = recs + (size_t)g * CAP;
    unsigned* cbase = csr2 + (size_t)g * CAP;
    for (int i = lo + t; i < hi; i += 1024) {
        uint2 r = base[i];
        int sl = r.x & 4095, dl = (r.x >> 12) & 4095;
        int pos = atomicAdd(&cur[dl], 1);
        float wf = __uint_as_float(r.y) * rss[sl];
        cbase[pos] = (unsigned)sl | ((unsigned)__half_as_ushort(__float2half(wf)) << 16);
    }
}

// ---------------- agg layer 1: half-wave per node (round-4 form, padded, uint4 recs) ----------------
__global__ __launch_bounds__(256) void k_agg1(const unsigned* __restrict__ fx,   // [NN*32]
                                              const unsigned* __restrict__ csr2,
                                              const int* __restrict__ offs,
                                              const int* __restrict__ degd,
                                              const float* __restrict__ rsd,
                                              unsigned* __restrict__ m1) {      // [NN*32]
    int bid = blockIdx.x;                       // NN/8 blocks
    int xcd = bid & 7, idx = bid >> 3;
    int g = xcd * 4 + (idx >> 9);
    int node0 = g * PP + (idx & 511) * 8;
    int lane = threadIdx.x & 63, wv = threadIdx.x >> 6;
    int half = lane >> 5, sl = lane & 31;
    int v = node0 + wv * 2 + half;
    int o = offs[v], cnt = degd[v];             // cnt % 4 == 0
    const unsigned* hp = fx + (size_t)((unsigned)(g * PP) * 32) + sl;
    float ax0 = 0.f, ay0 = 0.f, ax1 = 0.f, ay1 = 0.f;
    for (int i = 0; i < cnt; i += 4) {
        uint4 rr = *(const uint4*)(csr2 + o + i);
        unsigned g0 = hp[(rr.x & 4095) * 32];
        unsigned g1 = hp[(rr.y & 4095) * 32];
        unsigned g2 = hp[(rr.z & 4095) * 32];
        unsigned g3 = hp[(rr.w & 4095) * 32];
        float w0 = w16(rr.x), w1 = w16(rr.y), w2 = w16(rr.z), w3 = w16(rr.w);
        ax0 += w0 * bflo(g0); ay0 += w0 * bfhi(g0);
        ax1 += w1 * bflo(g1); ay1 += w1 * bfhi(g1);
        ax0 += w2 * bflo(g2); ay0 += w2 * bfhi(g2);
        ax1 += w3 * bflo(g3); ay1 += w3 * bfhi(g3);
    }
    float rd = rsd[v];
    m1[(size_t)v * 32 + sl] = pack2bf((ax0 + ax1) * rd, (ay0 + ay1) * rd);
}

// ---------------- agg layer 2: wave per 2 nodes, 8 outstanding gathers ----------------
__global__ __launch_bounds__(256) void k_agg2(const unsigned* __restrict__ h1,   // [NN*64]
                                              const unsigned* __restrict__ csr2,
                                              const int* __restrict__ offs,
                                              const int* __restrict__ degd,
                                              const float* __restrict__ rsd,
                                              unsigned* __restrict__ m2) {       // [NN*64]
    int bid = blockIdx.x;                        // NN/8 blocks
    int xcd = bid & 7, idx = bid >> 3;           // idx 0..2047
    int g = xcd * 4 + (idx >> 9);
    int node0 = g * PP + (idx & 511) * 4;
    int lane = threadIdx.x & 63, wv = threadIdx.x >> 6;
    int va = node0 + wv, vb = va + 2048;         // same graph
    int oa = offs[va], ca = degd[va];            // counts % 4 == 0
    int ob = offs[vb], cb = degd[vb];
    const unsigned* hp = h1 + (size_t)((unsigned)(g * PP) * 64) + lane;
    float A0 = 0.f, A1 = 0.f, B0 = 0.f, B1 = 0.f;
    int c0 = ca < cb ? ca : cb;
    int cm = ca < cb ? cb : ca;
    int i = 0;
    for (; i < c0; i += 4) {                     // dual-node interleave: 8 gathers in flight
        uint4 ra = *(const uint4*)(csr2 + oa + i);
        uint4 rb = *(const uint4*)(csr2 + ob + i);
        unsigned ga0 = hp[(ra.x & 4095) * 64];
        unsigned ga1 = hp[(ra.y & 4095) * 64];
        unsigned ga2 = hp[(ra.z & 4095) * 64];
        unsigned ga3 = hp[(ra.w & 4095) * 64];
        unsigned gb0 = hp[(rb.x & 4095) * 64];
        unsigned gb1 = hp[(rb.y & 4095) * 64];
        unsigned gb2 = hp[(rb.z & 4095) * 64];
        unsigned gb3 = hp[(rb.w & 4095) * 64];
        float wa0 = w16(ra.x), wa1 = w16(ra.y), wa2 = w16(ra.z), wa3 = w16(ra.w);
        float wb0 = w16(rb.x), wb1 = w16(rb.y), wb2 = w16(rb.z), wb3 = w16(rb.w);
        A0 += wa0 * bflo(ga0); A1 += wa0 * bfhi(ga0);
        A0 += wa1 * bflo(ga1); A1 += wa1 * bfhi(ga1);
        A0 += wa2 * bflo(ga2); A1 += wa2 * bfhi(ga2);
        A0 += wa3 * bflo(ga3); A1 += wa3 * bfhi(ga3);
        B0 += wb0 * bflo(gb0); B1 += wb0 * bfhi(gb0);
        B0 += wb1 * bflo(gb1); B1 += wb1 * bfhi(gb1);
        B0 += wb2 * bflo(gb2); B1 += wb2 * bfhi(gb2);
        B0 += wb3 * bflo(gb3); B1 += wb3 * bfhi(gb3);
    }
    if (i < cm) {                                // remainder: exactly one node has extra
        int ot = (ca > cb) ? oa : ob;
        float E0 = 0.f, E1 = 0.f, F0 = 0.f, F1 = 0.f;
        for (; i < cm; i += 4) {
            uint4 rr = *(const uint4*)(csr2 + ot + i);
            unsigned g0 = hp[(rr.x & 4095) * 64];
            unsigned g1 = hp[(rr.y & 4095) * 64];
            unsigned g2 = hp[(rr.z & 4095) * 64];
            unsigned g3 = hp[(rr.w & 4095) * 64];
            float w0 = w16(rr.x), w1 = w16(rr.y), w2 = w16(rr.z), w3 = w16(rr.w);
            E0 += w0 * bflo(g0); E1 += w0 * bfhi(g0);
            F0 += w1 * bflo(g1); F1 += w1 * bfhi(g1);
            E0 += w2 * bflo(g2); E1 += w2 * bfhi(g2);
            F0 += w3 * bflo(g3); F1 += w3 * bfhi(g3);
        }
        if (ca > cb) { A0 += E0 + F0; A1 += E1 + F1; }
        else         { B0 += E0 + F0; B1 += E1 + F1; }
    }
    float rda = rsd[va], rdb = rsd[vb];
    m2[(size_t)va * 64 + lane] = pack2bf(A0 * rda, A1 * rda);
    m2[(size_t)vb * 64 + lane] = pack2bf(B0 * rdb, B1 * rdb);
}

// ---------------- MFMA GEMM (bf16 out) + fused column-stat partials ----------------
template <int K>
__global__ __launch_bounds__(256) void k_gemm(const short* __restrict__ A,
                                              const short* __restrict__ PW,
                                              unsigned short* __restrict__ C,   // bf16 out
                                              float* __restrict__ part) {
    __shared__ float s1[HH], s2[HH];
    int t = threadIdx.x;
    if (t < HH) { s1[t] = 0.f; s2[t] = 0.f; }
    __syncthreads();
    int wv = t >> 6, lane = t & 63;
    int tile = blockIdx.x * 4 + wv;              // 16-row tile; grid = NN/64
    int m = lane & 15, quad = lane >> 4;
    int row = tile * 16 + m;
    bf16x8 a[K / 32];
#pragma unroll
    for (int kt = 0; kt < K / 32; kt++)
        a[kt] = *(const bf16x8*)(A + (size_t)row * K + kt * 32 + quad * 8);
#pragma unroll
    for (int nt = 0; nt < 8; nt++) {
        f32x4 acc = {0.f, 0.f, 0.f, 0.f};
#pragma unroll
        for (int kt = 0; kt < K / 32; kt++) {
            bf16x8 b = *(const bf16x8*)(PW + ((size_t)(kt * 8 + nt) * 64 + lane) * 8);
            acc = __builtin_amdgcn_mfma_f32_16x16x32_bf16(a[kt], b, acc, 0, 0, 0);
        }
        int col = nt * 16 + m;
        int r0 = tile * 16 + quad * 4;
        float ps = 0.f, pq = 0.f;
#pragma unroll
        for (int r = 0; r < 4; r++) {
            C[(size_t)(r0 + r) * HH + col] = (unsigned short)f2bf(acc[r]);
            ps += acc[r]; pq += acc[r] * acc[r];
        }
        atomicAdd(&s1[col], ps);
        atomicAdd(&s2[col], pq);
    }
    __syncthreads();
    if (t < HH) {
        part[blockIdx.x * 256 + t]      = s1[t];
        part[blockIdx.x * 256 + HH + t] = s2[t];
    }
}

// ---------------- stage-1 reduction of gemm partials ----------------
__global__ __launch_bounds__(256) void k_red(const float* __restrict__ part,
                                             float* __restrict__ pb) {
    int t = threadIdx.x, b = blockIdx.x;        // 64 blocks
    float s = 0.f;
    for (int r = 0; r < 32; r++) s += part[(size_t)(b * 32 + r) * 256 + t];
    pb[b * 256 + t] = s;
}

// ---------------- reduce + norm coefficients ----------------
__global__ void k_coef(const float* __restrict__ pb, const float* __restrict__ gamma,
                       const float* __restrict__ beta, const float* __restrict__ alpha,
                       float* __restrict__ ab) {
    int t = threadIdx.x;                         // 256 threads
    float s = 0.f;
    for (int b = 0; b < 64; b++) s += pb[b * 256 + t];
    __shared__ float sh[256];
    sh[t] = s;
    __syncthreads();
    if (t < 128) {
        float mu = sh[t] * (1.f / NN);
        float e2 = sh[128 + t] * (1.f / NN);
        float al = alpha[t];
        float var = e2 - (2.f * al - al * al) * mu * mu;
        float a = rsqrtf(var + EPSV) * gamma[t];
        ab[t] = a;
        ab[HH + t] = beta[t] - al * mu * a;
    }
}

// ---------------- fused norm + leaky-relu (in-place bf16) + per-graph readout ----------------
template <bool WRITE>
__global__ __launch_bounds__(256) void k_normro(unsigned* __restrict__ h,       // bf16 pairs
                                                const float* __restrict__ ab,
                                                float* __restrict__ racc) {
    int fp = threadIdx.x & 63;                   // feature pair
    int q  = threadIdx.x >> 6;                   // 0..3
    int node0 = blockIdx.x * 64;                 // one graph per block
    int g = node0 / PP;
    float a0 = ab[2 * fp], a1 = ab[2 * fp + 1];
    float b0 = ab[HH + 2 * fp], b1 = ab[HH + 2 * fp + 1];
    float s0 = 0.f, s1 = 0.f;
    for (int i = q; i < 64; i += 4) {
        size_t idx = (size_t)(node0 + i) * 64 + fp;
        unsigned v = h[idx];
        float x0 = fmaf(a0, bflo(v), b0); x0 = x0 > 0.f ? x0 : SLOPEV * x0;
        float x1 = fmaf(a1, bfhi(v), b1); x1 = x1 > 0.f ? x1 : SLOPEV * x1;
        if (WRITE) h[idx] = pack2bf(x0, x1);
        s0 += x0; s1 += x1;
    }
    __shared__ float sh[512];
    sh[threadIdx.x] = s0;
    sh[256 + threadIdx.x] = s1;
    __syncthreads();
    if (q == 0) {
        float t0 = s0 + sh[64 + fp] + sh[128 + fp] + sh[192 + fp];
        float t1 = s1 + sh[256 + 64 + fp] + sh[256 + 128 + fp] + sh[256 + 192 + fp];
        atomicAdd(&racc[g * HH + 2 * fp],     t0);
        atomicAdd(&racc[g * HH + 2 * fp + 1], t1);
    }
}

// ---------------- final head ----------------
__global__ void k_final(const float* __restrict__ racc1, const float* __restrict__ racc2,
                        const float* __restrict__ Wc, float* __restrict__ out) {
    int t = threadIdx.x;                         // 512 = 32*16
    int b = t >> 4, o = t & 15;
    float acc = 0.f;
    for (int f = 0; f < HH; f++) acc += racc1[b * HH + f] * Wc[o * (2 * HH) + f];
    for (int f = 0; f < HH; f++) acc += racc2[b * HH + f] * Wc[o * (2 * HH) + HH + f];
    out[t] = acc * (1.f / PP);
}

extern "C" void kernel_launch(void* const* d_in, const int* in_sizes, int n_in,
                              void* d_out, int out_size, void* d_ws, size_t ws_size,
                              hipStream_t stream) {
    const float* features = (const float*)d_in[0];
    const float* ew       = (const float*)d_in[1];
    const int*   src      = (const int*)d_in[2];
    const int*   dst      = (const int*)d_in[3];
    const float* W1       = (const float*)d_in[4];
    const float* W2       = (const float*)d_in[5];
    const float* Wc       = (const float*)d_in[6];
    const float* gamma1   = (const float*)d_in[7];
    const float* beta1    = (const float*)d_in[8];
    const float* alpha1   = (const float*)d_in[9];
    const float* gamma2   = (const float*)d_in[10];
    const float* beta2    = (const float*)d_in[11];
    const float* alpha2   = (const float*)d_in[12];
    float* out = (float*)d_out;

    char* w = (char*)d_ws;
    // misc block [0, 1 MB)
    int*    gcur   = (int*)(w + 0);                         // 32 * 16 ints
    float*  racc1  = (float*)(w + (16u << 10));             // 16 KB
    float*  racc2  = (float*)(w + (32u << 10));             // contiguous with racc1
    float*  ab1    = (float*)(w + (48u << 10));
    float*  ab2    = (float*)(w + (52u << 10));
    unsigned short* pw1 = (unsigned short*)(w + (64u << 10));   // 16 KB
    unsigned short* pw2 = (unsigned short*)(w + (80u << 10));   // 32 KB
    float*  pb     = (float*)(w + (128u << 10));            // 64 KB
    // arrays
    float*  rs_s   = (float*)(w + (1024u << 10));           // 512 KB
    float*  rsd    = (float*)(w + (1536u << 10));           // 512 KB
    int*    degd   = (int*)(w + (2048u << 10));             // 512 KB
    int*    offs   = (int*)(w + (2560u << 10));             // 512 KB
    float*  part   = (float*)(w + (3u << 20));              // 2 MB: 3..5
    int*    shist  = (int*)(w + (5u << 20));                // 4 MB: 5..9
    int*    dhist  = (int*)(w + (9u << 20));                // 4 MB: 9..13
    unsigned* csr2 = (unsigned*)(w + (13u << 20));          // 10 MB: 13..23
    unsigned* mbuf = (unsigned*)(w + (23u << 20));          // 32 MB: 23..55
    unsigned* hbuf = (unsigned*)(w + (55u << 20));          // 32 MB: 55..87
    uint2*    recs = (uint2*)(w + (87u << 20));             // 20 MB: 87..107
    unsigned* fx   = (unsigned*)(w + (107u << 20));         // 16 MB: 107..123

    // prep (cvt + init + packw fused) + zero pad region of csr2
    k_prep<<<16397, 256, 0, stream>>>(features, fx, W1, pw1, W2, pw2, gcur, racc1);
    hipMemsetAsync(csr2, 0, (size_t)BG * CAP * sizeof(unsigned), stream);

    // CSR build
    k_part<<<EE / 4096, 256, 0, stream>>>(src, dst, ew, gcur, recs);
    k_hist<<<BG * 8, 1024, 0, stream>>>(recs, gcur, shist, dhist);
    k_offs<<<BG, 1024, 0, stream>>>(shist, dhist, rs_s, rsd, degd, offs);
    k_place<<<BG * 8, 1024, 0, stream>>>(recs, gcur, dhist, rs_s, csr2);

    // ---- layer 1 ----
    k_agg1<<<NN / 8, 256, 0, stream>>>(fx, csr2, offs, degd, rsd, mbuf);
    k_gemm<64><<<NN / 64, 256, 0, stream>>>((const short*)mbuf, (const short*)pw1,
                                            (unsigned short*)hbuf, part);
    k_red<<<64, 256, 0, stream>>>(part, pb);
    k_coef<<<1, 256, 0, stream>>>(pb, gamma1, beta1, alpha1, ab1);
    k_normro<true><<<NN / 64, 256, 0, stream>>>(hbuf, ab1, racc1);

    // ---- layer 2 ----
    k_agg2<<<NN / 8, 256, 0, stream>>>(hbuf, csr2, offs, degd, rsd, mbuf);
    k_gemm<128><<<NN / 64, 256, 0, stream>>>((const short*)mbuf, (const short*)pw2,
                                             (unsigned short*)hbuf, part);
    k_red<<<64, 256, 0, stream>>>(part, pb);
    k_coef<<<1, 256, 0, stream>>>(pb, gamma2, beta2, alpha2, ab2);
    k_normro<false><<<NN / 64, 256, 0, stream>>>(hbuf, ab2, racc2);

    // ---- head ----
    k_final<<<1, 512, 0, stream>>>(racc1, racc2, Wc, out);
}

// Round 7
// 391.031 us; speedup vs baseline: 1.1398x; 1.0557x over previous
//
#include <hip/hip_runtime.h>
#include <hip/hip_fp16.h>

constexpr int NN   = 131072;   // total nodes
constexpr int PP   = 4096;     // nodes per graph
constexpr int BG   = 32;       // graphs
constexpr int EE   = 2097152;  // edges
constexpr int IND  = 64;
constexpr int HH   = 128;
constexpr int CAP  = 81920;    // per-graph slot capacity (65536 mean + pad4 + slack)
constexpr float EPSV   = 1e-5f;
constexpr float SLOPEV = 0.01f;

typedef short bf16x8 __attribute__((ext_vector_type(8)));
typedef float f32x4  __attribute__((ext_vector_type(4)));

__device__ __forceinline__ unsigned f2bf(float f) {
    unsigned u = __float_as_uint(f);
    return (u + 0x7FFFu + ((u >> 16) & 1u)) >> 16;      // RNE
}
__device__ __forceinline__ unsigned pack2bf(float lo, float hi) {
    return f2bf(lo) | (f2bf(hi) << 16);
}
__device__ __forceinline__ float bflo(unsigned p) { return __uint_as_float(p << 16); }
__device__ __forceinline__ float bfhi(unsigned p) { return __uint_as_float(p & 0xFFFF0000u); }
__device__ __forceinline__ float w16(unsigned r) {
    return __half2float(__ushort_as_half((unsigned short)(r >> 16)));
}

// ---------------- W -> MFMA B-fragment prepack (device body) ----------------
template <int K>
__device__ __forceinline__ void packw_body(const float* __restrict__ W,
                                           unsigned short* __restrict__ pw, int t) {
    if (t >= K * 16) return;
    int lane = t & 63, nt = (t >> 6) & 7, kt = t >> 9;
    int kbase = kt * 32 + ((lane >> 4) & 3) * 8;
    int col   = nt * 16 + (lane & 15);
    for (int j = 0; j < 8; j++)
        pw[t * 8 + j] = (unsigned short)f2bf(W[(kbase + j) * HH + col]);
}

// ---------------- fused prep: feature cvt + init + weight prepack + csr2 zero ----------------
__global__ __launch_bounds__(256) void k_prep(const float* __restrict__ features,
                                              unsigned* __restrict__ fx,
                                              const float* __restrict__ W1,
                                              unsigned short* __restrict__ pw1,
                                              const float* __restrict__ W2,
                                              unsigned short* __restrict__ pw2,
                                              int* __restrict__ gcur,
                                              float* __restrict__ racc,
                                              unsigned* __restrict__ csr2) {
    int b = blockIdx.x, t = threadIdx.x;
    if (b < 16384) {                    // bf16 convert: NN*IND/2 = 16384*256 words
        int i = b * 256 + t;
        float2 v = ((const float2*)features)[i];
        fx[i] = pack2bf(v.x, v.y);
        return;
    }
    if (b == 16384) {                   // init cursors + readout accumulators
        if (t < BG) gcur[t * 16] = t * CAP;
        for (int i = t; i < 2 * BG * HH; i += 256) racc[i] = 0.f;
        return;
    }
    if (b < 16389) { packw_body<64>(W1, pw1, (b - 16385) * 256 + t); return; }
    if (b < 16397) { packw_body<128>(W2, pw2, (b - 16389) * 256 + t); return; }
    // zero csr2 pad region: BG*CAP words = 163840 uint4 = 2560 blocks
    ((uint4*)csr2)[(b - 16397) * 256 + t] = make_uint4(0, 0, 0, 0);
}

// ---------------- pass 1: 32-way partition of edges by graph ----------------
__global__ __launch_bounds__(256) void k_part(const int* __restrict__ src,
                                              const int* __restrict__ dst,
                                              const float* __restrict__ ew,
                                              int* __restrict__ gcur,
                                              uint2* __restrict__ recs) {
    __shared__ int cnt[32];
    __shared__ int start[32];
    __shared__ int gbase[32];
    __shared__ uint2 stage[4096];
    int t = threadIdx.x;
    int ebase = blockIdx.x * 4096;
    if (t < 32) cnt[t] = 0;
    __syncthreads();
    int es[16]; int ed[16]; float ev[16];
#pragma unroll
    for (int k = 0; k < 16; k++) {
        int e = ebase + k * 256 + t;
        es[k] = src[e]; ed[k] = dst[e]; ev[k] = ew[e];
        atomicAdd(&cnt[es[k] >> 12], 1);
    }
    __syncthreads();
    if (t == 0) {
        int run = 0;
        for (int g = 0; g < 32; g++) { start[g] = run; run += cnt[g]; }
    }
    __syncthreads();
    if (t < 32) {
        gbase[t] = atomicAdd(&gcur[t * 16], cnt[t]);
        cnt[t] = start[t];                      // becomes cursor
    }
    __syncthreads();
#pragma unroll
    for (int k = 0; k < 16; k++) {
        int g = es[k] >> 12;
        int pos = atomicAdd(&cnt[g], 1);
        stage[pos] = make_uint2((unsigned)(es[k] & 4095) | ((unsigned)(ed[k] & 4095) << 12) |
                                ((unsigned)g << 24), __float_as_uint(ev[k]));
    }
    __syncthreads();
    for (int i = t; i < 4096; i += 256) {
        uint2 r = stage[i];
        int g = r.x >> 24;
        recs[gbase[g] + (i - start[g])] = r;
    }
}

// ---------------- build phase A: per-(graph,chunk) histograms ----------------
__global__ __launch_bounds__(1024) void k_hist(const uint2* __restrict__ recs,
                                               const int* __restrict__ gcur,
                                               int* __restrict__ shist,
                                               int* __restrict__ dhist) {
    __shared__ int hs[4096];
    __shared__ int hd[4096];
    int t = threadIdx.x;
    int g = blockIdx.x >> 3, c = blockIdx.x & 7;
    int n = gcur[g * 16] - g * CAP;
    int lo = (n * c) >> 3, hi = (n * (c + 1)) >> 3;
    ((int4*)hs)[t] = make_int4(0, 0, 0, 0);
    ((int4*)hd)[t] = make_int4(0, 0, 0, 0);
    __syncthreads();
    const uint2* base = recs + (size_t)g * CAP;
    for (int i = lo + t; i < hi; i += 1024) {
        unsigned x = base[i].x;
        atomicAdd(&hs[x & 4095], 1);
        atomicAdd(&hd[(x >> 12) & 4095], 1);
    }
    __syncthreads();
    ((int4*)(shist + (size_t)blockIdx.x * 4096))[t] = ((int4*)hs)[t];
    ((int4*)(dhist + (size_t)blockIdx.x * 4096))[t] = ((int4*)hd)[t];
}

// ---------------- build phase B: degrees, rsqrt, padded offsets, chunk cursor bases ----------------
__global__ __launch_bounds__(1024) void k_offs(int* __restrict__ shist,
                                               int* __restrict__ dhist,
                                               float* __restrict__ rs_s,
                                               float* __restrict__ rsd,
                                               int* __restrict__ degd,
                                               int* __restrict__ offs) {
    __shared__ int partial[1024];
    int t = threadIdx.x, g = blockIdx.x;
    int sdeg[4] = {0, 0, 0, 0}, ddeg[4] = {0, 0, 0, 0};
#pragma unroll
    for (int c = 0; c < 8; c++) {
        int4 sv = ((const int4*)(shist + (size_t)(g * 8 + c) * 4096))[t];
        int4 dv = ((const int4*)(dhist + (size_t)(g * 8 + c) * 4096))[t];
        sdeg[0] += sv.x; sdeg[1] += sv.y; sdeg[2] += sv.z; sdeg[3] += sv.w;
        ddeg[0] += dv.x; ddeg[1] += dv.y; ddeg[2] += dv.z; ddeg[3] += dv.w;
    }
    int pdeg[4];
#pragma unroll
    for (int j = 0; j < 4; j++) {
        int idx = t * 4 + j;
        int vs = sdeg[j]; if (vs < 1) vs = 1;
        rs_s[g * PP + idx] = rsqrtf((float)vs);
        int vd = ddeg[j]; if (vd < 1) vd = 1;
        rsd[g * PP + idx]  = rsqrtf((float)vd);
        pdeg[j] = (ddeg[j] + 3) & ~3;           // padded to multiple of 4
        degd[g * PP + idx] = pdeg[j];           // agg loops run over padded count
    }
    partial[t] = pdeg[0] + pdeg[1] + pdeg[2] + pdeg[3];
    __syncthreads();
    for (int off = 1; off < 1024; off <<= 1) {
        int v = partial[t];
        int add = (t >= off) ? partial[t - off] : 0;
        __syncthreads();
        partial[t] = v + add;
        __syncthreads();
    }
    int run = (t == 0) ? 0 : partial[t - 1];
#pragma unroll
    for (int j = 0; j < 4; j++) {
        int idx = t * 4 + j;
        offs[g * PP + idx] = g * CAP + run;
        int nb = run;                           // true edges placed at segment start
        for (int c = 0; c < 8; c++) {
            size_t hidx = (size_t)(g * 8 + c) * 4096 + idx;
            int v = dhist[hidx];
            dhist[hidx] = nb;                   // per-chunk cursor base (graph-relative)
            nb += v;
        }
        run += pdeg[j];                         // pad region stays zero
    }
}

// ---------------- build phase C: counting-sort placement ----------------
__global__ __launch_bounds__(1024) void k_place(const uint2* __restrict__ recs,
                                                const int* __restrict__ gcur,
                                                const int* __restrict__ dhist,
                                                const float* __restrict__ rs_s,
                                                unsigned* __restrict__ csr2) {
    __shared__ int cur[4096];
    __shared__ float rss[4096];
    int t = threadIdx.x;
    int g = blockIdx.x >> 3, c = blockIdx.x & 7;
    int n = gcur[g * 16] - g * CAP;
    int lo = (n * c) >> 3, hi = (n * (c + 1)) >> 3;
    ((int4*)cur)[t] = ((const int4*)(dhist + (size_t)blockIdx.x * 4096))[t];
    ((float4*)rss)[t] = ((const float4*)(rs_s + (size_t)g * PP))[t];
    __syncthreads();
    const uint2* base = recs + (size_t)g * CAP;
    unsigned* cbase = csr2 + (size_t)g * CAP;
    for (int i = lo + t; i < hi; i += 1024) {
        uint2 r = base[i];
        int sl = r.x & 4095, dl = (r.x >> 12) & 4095;
        int pos = atomicAdd(&cur[dl], 1);
        float wf = __uint_as_float(r.y) * rss[sl];
        cbase[pos] = (unsigned)sl | ((unsigned)__half_as_ushort(__float2half(wf)) << 16);
    }
}

// ================= FUSED layer 1: aggregate (half-wave/node) -> LDS -> MFMA =================
__global__ __launch_bounds__(256) void k_aggemm1(const unsigned* __restrict__ fx,   // [NN*32]
                                                 const unsigned* __restrict__ csr2,
                                                 const int* __restrict__ offs,
                                                 const int* __restrict__ degd,
                                                 const float* __restrict__ rsd,
                                                 const short* __restrict__ PW,
                                                 unsigned short* __restrict__ C,
                                                 float* __restrict__ part) {
    constexpr int WP = 36;                       // padded row stride (words); 36%4==0
    __shared__ unsigned lds[64 * WP];            // 9.2 KB
    __shared__ float s1[HH], s2[HH];
    int t = threadIdx.x;
    if (t < HH) { s1[t] = 0.f; s2[t] = 0.f; }
    int bid = blockIdx.x;                        // 2048 blocks
    int xcd = bid & 7, idx = bid >> 3;           // idx 0..255
    int g = xcd * 4 + (idx >> 6);                // XCD x owns graphs 4x..4x+3
    int node0 = g * PP + (idx & 63) * 64;        // 64 nodes per block, one graph
    int lane = t & 63, wv = t >> 6;
    int half = lane >> 5, sl = lane & 31;
    const unsigned* hp = fx + (size_t)((unsigned)(g * PP) * 32) + sl;
    for (int p = 0; p < 8; p++) {                // 16 nodes per wave, 2 per pass
        int lr = wv * 16 + p * 2 + half;         // local row
        int v = node0 + lr;
        int o = offs[v], cnt = degd[v];          // cnt % 4 == 0
        float ax0 = 0.f, ay0 = 0.f, ax1 = 0.f, ay1 = 0.f;
        for (int i = 0; i < cnt; i += 4) {
            uint4 rr = *(const uint4*)(csr2 + o + i);
            unsigned g0 = hp[(rr.x & 4095) * 32];
            unsigned g1 = hp[(rr.y & 4095) * 32];
            unsigned g2 = hp[(rr.z & 4095) * 32];
            unsigned g3 = hp[(rr.w & 4095) * 32];
            float w0 = w16(rr.x), w1 = w16(rr.y), w2 = w16(rr.z), w3 = w16(rr.w);
            ax0 += w0 * bflo(g0); ay0 += w0 * bfhi(g0);
            ax1 += w1 * bflo(g1); ay1 += w1 * bfhi(g1);
            ax0 += w2 * bflo(g2); ay0 += w2 * bfhi(g2);
            ax1 += w3 * bflo(g3); ay1 += w3 * bfhi(g3);
        }
        float rd = rsd[v];
        lds[lr * WP + sl] = pack2bf((ax0 + ax1) * rd, (ay0 + ay1) * rd);
    }
    __syncthreads();
    // MFMA: wave wv -> local rows wv*16..+15, K=64
    int m = lane & 15, quad = lane >> 4;
    bf16x8 a[2];
#pragma unroll
    for (int kt = 0; kt < 2; kt++)
        a[kt] = *(const bf16x8*)&lds[(wv * 16 + m) * WP + kt * 16 + quad * 4];
#pragma unroll
    for (int nt = 0; nt < 8; nt++) {
        f32x4 acc = {0.f, 0.f, 0.f, 0.f};
#pragma unroll
        for (int kt = 0; kt < 2; kt++) {
            bf16x8 b = *(const bf16x8*)(PW + ((size_t)(kt * 8 + nt) * 64 + lane) * 8);
            acc = __builtin_amdgcn_mfma_f32_16x16x32_bf16(a[kt], b, acc, 0, 0, 0);
        }
        int col = nt * 16 + m;
        int r0 = node0 + wv * 16 + quad * 4;
        float ps = 0.f, pq = 0.f;
#pragma unroll
        for (int r = 0; r < 4; r++) {
            C[(size_t)(r0 + r) * HH + col] = (unsigned short)f2bf(acc[r]);
            ps += acc[r]; pq += acc[r] * acc[r];
        }
        atomicAdd(&s1[col], ps);
        atomicAdd(&s2[col], pq);
    }
    __syncthreads();
    if (t < HH) {
        part[bid * 256 + t]      = s1[t];
        part[bid * 256 + HH + t] = s2[t];
    }
}

// ================= FUSED layer 2: aggregate (wave/2 nodes) -> LDS -> MFMA =================
__global__ __launch_bounds__(256) void k_aggemm2(const unsigned* __restrict__ h1,   // [NN*64]
                                                 const unsigned* __restrict__ csr2,
                                                 const int* __restrict__ offs,
                                                 const int* __restrict__ degd,
                                                 const float* __restrict__ rsd,
                                                 const short* __restrict__ PW,
                                                 unsigned short* __restrict__ C,
                                                 float* __restrict__ part) {
    constexpr int WP = 68;                       // padded row stride (words); 68%4==0
    __shared__ unsigned lds[64 * WP];            // 17.4 KB
    __shared__ float s1[HH], s2[HH];
    int t = threadIdx.x;
    if (t < HH) { s1[t] = 0.f; s2[t] = 0.f; }
    int bid = blockIdx.x;                        // 2048 blocks
    int xcd = bid & 7, idx = bid >> 3;
    int g = xcd * 4 + (idx >> 6);
    int node0 = g * PP + (idx & 63) * 64;
    int lane = t & 63, wv = t >> 6;
    const unsigned* hp = h1 + (size_t)((unsigned)(g * PP) * 64) + lane;
    for (int p = 0; p < 8; p++) {                // dual-node interleave: rows p, p+8
        int va = node0 + wv * 16 + p, vb = va + 8;
        int oa = offs[va], ca = degd[va];
        int ob = offs[vb], cb = degd[vb];
        float A0 = 0.f, A1 = 0.f, B0 = 0.f, B1 = 0.f;
        int c0 = ca < cb ? ca : cb;
        int cm = ca < cb ? cb : ca;
        int i = 0;
        for (; i < c0; i += 4) {                 // 8 gathers in flight
            uint4 ra = *(const uint4*)(csr2 + oa + i);
            uint4 rb = *(const uint4*)(csr2 + ob + i);
            unsigned ga0 = hp[(ra.x & 4095) * 64];
            unsigned ga1 = hp[(ra.y & 4095) * 64];
            unsigned ga2 = hp[(ra.z & 4095) * 64];
            unsigned ga3 = hp[(ra.w & 4095) * 64];
            unsigned gb0 = hp[(rb.x & 4095) * 64];
            unsigned gb1 = hp[(rb.y & 4095) * 64];
            unsigned gb2 = hp[(rb.z & 4095) * 64];
            unsigned gb3 = hp[(rb.w & 4095) * 64];
            float wa0 = w16(ra.x), wa1 = w16(ra.y), wa2 = w16(ra.z), wa3 = w16(ra.w);
            float wb0 = w16(rb.x), wb1 = w16(rb.y), wb2 = w16(rb.z), wb3 = w16(rb.w);
            A0 += wa0 * bflo(ga0); A1 += wa0 * bfhi(ga0);
            A0 += wa1 * bflo(ga1); A1 += wa1 * bfhi(ga1);
            A0 += wa2 * bflo(ga2); A1 += wa2 * bfhi(ga2);
            A0 += wa3 * bflo(ga3); A1 += wa3 * bfhi(ga3);
            B0 += wb0 * bflo(gb0); B1 += wb0 * bfhi(gb0);
            B0 += wb1 * bflo(gb1); B1 += wb1 * bfhi(gb1);
            B0 += wb2 * bflo(gb2); B1 += wb2 * bfhi(gb2);
            B0 += wb3 * bflo(gb3); B1 += wb3 * bfhi(gb3);
        }
        if (i < cm) {                            // remainder: one node has extra
            int ot = (ca > cb) ? oa : ob;
            float E0 = 0.f, E1 = 0.f, F0 = 0.f, F1 = 0.f;
            for (; i < cm; i += 4) {
                uint4 rr = *(const uint4*)(csr2 + ot + i);
                unsigned g0 = hp[(rr.x & 4095) * 64];
                unsigned g1 = hp[(rr.y & 4095) * 64];
                unsigned g2 = hp[(rr.z & 4095) * 64];
                unsigned g3 = hp[(rr.w & 4095) * 64];
                float w0 = w16(rr.x), w1 = w16(rr.y), w2 = w16(rr.z), w3 = w16(rr.w);
                E0 += w0 * bflo(g0); E1 += w0 * bfhi(g0);
                F0 += w1 * bflo(g1); F1 += w1 * bfhi(g1);
                E0 += w2 * bflo(g2); E1 += w2 * bfhi(g2);
                F0 += w3 * bflo(g3); F1 += w3 * bfhi(g3);
            }
            if (ca > cb) { A0 += E0 + F0; A1 += E1 + F1; }
            else         { B0 += E0 + F0; B1 += E1 + F1; }
        }
        float rda = rsd[va], rdb = rsd[vb];
        lds[(wv * 16 + p) * WP + lane]     = pack2bf(A0 * rda, A1 * rda);
        lds[(wv * 16 + p + 8) * WP + lane] = pack2bf(B0 * rdb, B1 * rdb);
    }
    __syncthreads();
    // MFMA: wave wv -> local rows wv*16..+15, K=128
    int m = lane & 15, quad = lane >> 4;
    bf16x8 a[4];
#pragma unroll
    for (int kt = 0; kt < 4; kt++)
        a[kt] = *(const bf16x8*)&lds[(wv * 16 + m) * WP + kt * 16 + quad * 4];
#pragma unroll
    for (int nt = 0; nt < 8; nt++) {
        f32x4 acc = {0.f, 0.f, 0.f, 0.f};
#pragma unroll
        for (int kt = 0; kt < 4; kt++) {
            bf16x8 b = *(const bf16x8*)(PW + ((size_t)(kt * 8 + nt) * 64 + lane) * 8);
            acc = __builtin_amdgcn_mfma_f32_16x16x32_bf16(a[kt], b, acc, 0, 0, 0);
        }
        int col = nt * 16 + m;
        int r0 = node0 + wv * 16 + quad * 4;
        float ps = 0.f, pq = 0.f;
#pragma unroll
        for (int r = 0; r < 4; r++) {
            C[(size_t)(r0 + r) * HH + col] = (unsigned short)f2bf(acc[r]);
            ps += acc[r]; pq += acc[r] * acc[r];
        }
        atomicAdd(&s1[col], ps);
        atomicAdd(&s2[col], pq);
    }
    __syncthreads();
    if (t < HH) {
        part[bid * 256 + t]      = s1[t];
        part[bid * 256 + HH + t] = s2[t];
    }
}

// ---------------- stage-1 reduction of gemm partials ----------------
__global__ __launch_bounds__(256) void k_red(const float* __restrict__ part,
                                             float* __restrict__ pb) {
    int t = threadIdx.x, b = blockIdx.x;        // 64 blocks
    float s = 0.f;
    for (int r = 0; r < 32; r++) s += part[(size_t)(b * 32 + r) * 256 + t];
    pb[b * 256 + t] = s;
}

// ---------------- reduce + norm coefficients ----------------
__global__ void k_coef(const float* __restrict__ pb, const float* __restrict__ gamma,
                       const float* __restrict__ beta, const float* __restrict__ alpha,
                       float* __restrict__ ab) {
    int t = threadIdx.x;                         // 256 threads
    float s = 0.f;
    for (int b = 0; b < 64; b++) s += pb[b * 256 + t];
    __shared__ float sh[256];
    sh[t] = s;
    __syncthreads();
    if (t < 128) {
        float mu = sh[t] * (1.f / NN);
        float e2 = sh[128 + t] * (1.f / NN);
        float al = alpha[t];
        float var = e2 - (2.f * al - al * al) * mu * mu;
        float a = rsqrtf(var + EPSV) * gamma[t];
        ab[t] = a;
        ab[HH + t] = beta[t] - al * mu * a;
    }
}

// ---------------- fused norm + leaky-relu (in-place bf16) + per-graph readout ----------------
template <bool WRITE>
__global__ __launch_bounds__(256) void k_normro(unsigned* __restrict__ h,       // bf16 pairs
                                                const float* __restrict__ ab,
                                                float* __restrict__ racc) {
    int fp = threadIdx.x & 63;                   // feature pair
    int q  = threadIdx.x >> 6;                   // 0..3
    int node0 = blockIdx.x * 64;                 // one graph per block
    int g = node0 / PP;
    float a0 = ab[2 * fp], a1 = ab[2 * fp + 1];
    float b0 = ab[HH + 2 * fp], b1 = ab[HH + 2 * fp + 1];
    float s0 = 0.f, s1 = 0.f;
    for (int i = q; i < 64; i += 4) {
        size_t idx = (size_t)(node0 + i) * 64 + fp;
        unsigned v = h[idx];
        float x0 = fmaf(a0, bflo(v), b0); x0 = x0 > 0.f ? x0 : SLOPEV * x0;
        float x1 = fmaf(a1, bfhi(v), b1); x1 = x1 > 0.f ? x1 : SLOPEV * x1;
        if (WRITE) h[idx] = pack2bf(x0, x1);
        s0 += x0; s1 += x1;
    }
    __shared__ float sh[512];
    sh[threadIdx.x] = s0;
    sh[256 + threadIdx.x] = s1;
    __syncthreads();
    if (q == 0) {
        float t0 = s0 + sh[64 + fp] + sh[128 + fp] + sh[192 + fp];
        float t1 = s1 + sh[256 + 64 + fp] + sh[256 + 128 + fp] + sh[256 + 192 + fp];
        atomicAdd(&racc[g * HH + 2 * fp],     t0);
        atomicAdd(&racc[g * HH + 2 * fp + 1], t1);
    }
}

// ---------------- final head ----------------
__global__ void k_final(const float* __restrict__ racc1, const float* __restrict__ racc2,
                        const float* __restrict__ Wc, float* __restrict__ out) {
    int t = threadIdx.x;                         // 512 = 32*16
    int b = t >> 4, o = t & 15;
    float acc = 0.f;
    for (int f = 0; f < HH; f++) acc += racc1[b * HH + f] * Wc[o * (2 * HH) + f];
    for (int f = 0; f < HH; f++) acc += racc2[b * HH + f] * Wc[o * (2 * HH) + HH + f];
    out[t] = acc * (1.f / PP);
}

extern "C" void kernel_launch(void* const* d_in, const int* in_sizes, int n_in,
                              void* d_out, int out_size, void* d_ws, size_t ws_size,
                              hipStream_t stream) {
    const float* features = (const float*)d_in[0];
    const float* ew       = (const float*)d_in[1];
    const int*   src      = (const int*)d_in[2];
    const int*   dst      = (const int*)d_in[3];
    const float* W1       = (const float*)d_in[4];
    const float* W2       = (const float*)d_in[5];
    const float* Wc       = (const float*)d_in[6];
    const float* gamma1   = (const float*)d_in[7];
    const float* beta1    = (const float*)d_in[8];
    const float* alpha1   = (const float*)d_in[9];
    const float* gamma2   = (const float*)d_in[10];
    const float* beta2    = (const float*)d_in[11];
    const float* alpha2   = (const float*)d_in[12];
    float* out = (float*)d_out;

    char* w = (char*)d_ws;
    // misc block [0, 1 MB)
    int*    gcur   = (int*)(w + 0);                         // 32 * 16 ints
    float*  racc1  = (float*)(w + (16u << 10));             // 16 KB
    float*  racc2  = (float*)(w + (32u << 10));             // contiguous with racc1
    float*  ab1    = (float*)(w + (48u << 10));
    float*  ab2    = (float*)(w + (52u << 10));
    unsigned short* pw1 = (unsigned short*)(w + (64u << 10));   // 16 KB
    unsigned short* pw2 = (unsigned short*)(w + (80u << 10));   // 32 KB
    float*  pb     = (float*)(w + (128u << 10));            // 64 KB
    // arrays
    float*  rs_s   = (float*)(w + (1024u << 10));           // 512 KB
    float*  rsd    = (float*)(w + (1536u << 10));           // 512 KB
    int*    degd   = (int*)(w + (2048u << 10));             // 512 KB
    int*    offs   = (int*)(w + (2560u << 10));             // 512 KB
    float*  part   = (float*)(w + (3u << 20));              // 2 MB: 3..5
    int*    shist  = (int*)(w + (5u << 20));                // 4 MB: 5..9
    int*    dhist  = (int*)(w + (9u << 20));                // 4 MB: 9..13
    unsigned* csr2 = (unsigned*)(w + (13u << 20));          // 10 MB: 13..23
    unsigned* mbuf = (unsigned*)(w + (23u << 20));          // 32 MB: 23..55 (h2pre)
    unsigned* hbuf = (unsigned*)(w + (55u << 20));          // 32 MB: 55..87 (h1pre -> h1)
    uint2*    recs = (uint2*)(w + (87u << 20));             // 20 MB: 87..107
    unsigned* fx   = (unsigned*)(w + (107u << 20));         // 16 MB: 107..123

    // prep (cvt + init + packw + csr2 zero, fused)
    k_prep<<<18957, 256, 0, stream>>>(features, fx, W1, pw1, W2, pw2, gcur, racc1, csr2);

    // CSR build
    k_part<<<EE / 4096, 256, 0, stream>>>(src, dst, ew, gcur, recs);
    k_hist<<<BG * 8, 1024, 0, stream>>>(recs, gcur, shist, dhist);
    k_offs<<<BG, 1024, 0, stream>>>(shist, dhist, rs_s, rsd, degd, offs);
    k_place<<<BG * 8, 1024, 0, stream>>>(recs, gcur, dhist, rs_s, csr2);

    // ---- layer 1 (fused agg+gemm) ----
    k_aggemm1<<<NN / 64, 256, 0, stream>>>(fx, csr2, offs, degd, rsd,
                                           (const short*)pw1, (unsigned short*)hbuf, part);
    k_red<<<64, 256, 0, stream>>>(part, pb);
    k_coef<<<1, 256, 0, stream>>>(pb, gamma1, beta1, alpha1, ab1);
    k_normro<true><<<NN / 64, 256, 0, stream>>>(hbuf, ab1, racc1);

    // ---- layer 2 (fused agg+gemm; reads hbuf, writes mbuf) ----
    k_aggemm2<<<NN / 64, 256, 0, stream>>>(hbuf, csr2, offs, degd, rsd,
                                           (const short*)pw2, (unsigned short*)mbuf, part);
    k_red<<<64, 256, 0, stream>>>(part, pb);
    k_coef<<<1, 256, 0, stream>>>(pb, gamma2, beta2, alpha2, ab2);
    k_normro<false><<<NN / 64, 256, 0, stream>>>(mbuf, ab2, racc2);

    // ---- head ----
    k_final<<<1, 512, 0, stream>>>(racc1, racc2, Wc, out);
}

// Round 8
// 372.611 us; speedup vs baseline: 1.1962x; 1.0494x over previous
//
#include <hip/hip_runtime.h>
#include <hip/hip_fp16.h>

constexpr int NN   = 131072;   // total nodes
constexpr int PP   = 4096;     // nodes per graph
constexpr int BG   = 32;       // graphs
constexpr int EE   = 2097152;  // edges
constexpr int IND  = 64;
constexpr int HH   = 128;
constexpr int CAP  = 81920;    // per-graph slot capacity (65536 mean + pad4 + slack)
constexpr float EPSV   = 1e-5f;
constexpr float SLOPEV = 0.01f;

typedef short bf16x8 __attribute__((ext_vector_type(8)));
typedef float f32x4  __attribute__((ext_vector_type(4)));
typedef float f32x2  __attribute__((ext_vector_type(2)));

__device__ __forceinline__ unsigned f2bf(float f) {
    unsigned u = __float_as_uint(f);
    return (u + 0x7FFFu + ((u >> 16) & 1u)) >> 16;      // RNE
}
__device__ __forceinline__ unsigned pack2bf(float lo, float hi) {
    return f2bf(lo) | (f2bf(hi) << 16);
}
__device__ __forceinline__ float bflo(unsigned p) { return __uint_as_float(p << 16); }
__device__ __forceinline__ float bfhi(unsigned p) { return __uint_as_float(p & 0xFFFF0000u); }
__device__ __forceinline__ float w16(unsigned r) {
    return __half2float(__ushort_as_half((unsigned short)(r >> 16)));
}

// ---------------- W -> MFMA B-fragment prepack (device body) ----------------
template <int K>
__device__ __forceinline__ void packw_body(const float* __restrict__ W,
                                           unsigned short* __restrict__ pw, int t) {
    if (t >= K * 16) return;
    int lane = t & 63, nt = (t >> 6) & 7, kt = t >> 9;
    int kbase = kt * 32 + ((lane >> 4) & 3) * 8;
    int col   = nt * 16 + (lane & 15);
    for (int j = 0; j < 8; j++)
        pw[t * 8 + j] = (unsigned short)f2bf(W[(kbase + j) * HH + col]);
}

// ---------------- fused prep: feature cvt + init + weight prepack + csr2 zero ----------------
__global__ __launch_bounds__(256) void k_prep(const float* __restrict__ features,
                                              unsigned* __restrict__ fx,
                                              const float* __restrict__ W1,
                                              unsigned short* __restrict__ pw1,
                                              const float* __restrict__ W2,
                                              unsigned short* __restrict__ pw2,
                                              int* __restrict__ gcur,
                                              float* __restrict__ racc,
                                              unsigned* __restrict__ csr2) {
    int b = blockIdx.x, t = threadIdx.x;
    if (b < 16384) {                    // bf16 convert: NN*IND/2 = 16384*256 words
        int i = b * 256 + t;
        float2 v = ((const float2*)features)[i];
        fx[i] = pack2bf(v.x, v.y);
        return;
    }
    if (b == 16384) {                   // init cursors + readout accumulators
        if (t < BG) gcur[t * 16] = t * CAP;
        for (int i = t; i < 2 * BG * HH; i += 256) racc[i] = 0.f;
        return;
    }
    if (b < 16389) { packw_body<64>(W1, pw1, (b - 16385) * 256 + t); return; }
    if (b < 16397) { packw_body<128>(W2, pw2, (b - 16389) * 256 + t); return; }
    // zero csr2 pad region: BG*CAP words = 163840 uint4 = 2560 blocks
    ((uint4*)csr2)[(b - 16397) * 256 + t] = make_uint4(0, 0, 0, 0);
}

// ---------------- pass 1: 32-way partition of edges by graph ----------------
__global__ __launch_bounds__(256) void k_part(const int* __restrict__ src,
                                              const int* __restrict__ dst,
                                              const float* __restrict__ ew,
                                              int* __restrict__ gcur,
                                              uint2* __restrict__ recs) {
    __shared__ int cnt[32];
    __shared__ int start[32];
    __shared__ int gbase[32];
    __shared__ uint2 stage[4096];
    int t = threadIdx.x;
    int ebase = blockIdx.x * 4096;
    if (t < 32) cnt[t] = 0;
    __syncthreads();
    int es[16]; int ed[16]; float ev[16];
#pragma unroll
    for (int k = 0; k < 16; k++) {
        int e = ebase + k * 256 + t;
        es[k] = src[e]; ed[k] = dst[e]; ev[k] = ew[e];
        atomicAdd(&cnt[es[k] >> 12], 1);
    }
    __syncthreads();
    if (t == 0) {
        int run = 0;
        for (int g = 0; g < 32; g++) { start[g] = run; run += cnt[g]; }
    }
    __syncthreads();
    if (t < 32) {
        gbase[t] = atomicAdd(&gcur[t * 16], cnt[t]);
        cnt[t] = start[t];                      // becomes cursor
    }
    __syncthreads();
#pragma unroll
    for (int k = 0; k < 16; k++) {
        int g = es[k] >> 12;
        int pos = atomicAdd(&cnt[g], 1);
        stage[pos] = make_uint2((unsigned)(es[k] & 4095) | ((unsigned)(ed[k] & 4095) << 12) |
                                ((unsigned)g << 24), __float_as_uint(ev[k]));
    }
    __syncthreads();
    for (int i = t; i < 4096; i += 256) {
        uint2 r = stage[i];
        int g = r.x >> 24;
        recs[gbase[g] + (i - start[g])] = r;
    }
}

// ---------------- build phase A: per-(graph,chunk) histograms ----------------
__global__ __launch_bounds__(1024) void k_hist(const uint2* __restrict__ recs,
                                               const int* __restrict__ gcur,
                                               int* __restrict__ shist,
                                               int* __restrict__ dhist) {
    __shared__ int hs[4096];
    __shared__ int hd[4096];
    int t = threadIdx.x;
    int g = blockIdx.x >> 3, c = blockIdx.x & 7;
    int n = gcur[g * 16] - g * CAP;
    int lo = (n * c) >> 3, hi = (n * (c + 1)) >> 3;
    ((int4*)hs)[t] = make_int4(0, 0, 0, 0);
    ((int4*)hd)[t] = make_int4(0, 0, 0, 0);
    __syncthreads();
    const uint2* base = recs + (size_t)g * CAP;
    for (int i = lo + t; i < hi; i += 1024) {
        unsigned x = base[i].x;
        atomicAdd(&hs[x & 4095], 1);
        atomicAdd(&hd[(x >> 12) & 4095], 1);
    }
    __syncthreads();
    ((int4*)(shist + (size_t)blockIdx.x * 4096))[t] = ((int4*)hs)[t];
    ((int4*)(dhist + (size_t)blockIdx.x * 4096))[t] = ((int4*)hd)[t];
}

// ---------------- build phase B: degrees, rsqrt, padded offsets, chunk cursor bases ----------------
__global__ __launch_bounds__(1024) void k_offs(int* __restrict__ shist,
                                               int* __restrict__ dhist,
                                               float* __restrict__ rs_s,
                                               float* __restrict__ rsd,
                                               int* __restrict__ degd,
                                               int* __restrict__ offs) {
    __shared__ int partial[1024];
    int t = threadIdx.x, g = blockIdx.x;
    int sdeg[4] = {0, 0, 0, 0}, ddeg[4] = {0, 0, 0, 0};
#pragma unroll
    for (int c = 0; c < 8; c++) {
        int4 sv = ((const int4*)(shist + (size_t)(g * 8 + c) * 4096))[t];
        int4 dv = ((const int4*)(dhist + (size_t)(g * 8 + c) * 4096))[t];
        sdeg[0] += sv.x; sdeg[1] += sv.y; sdeg[2] += sv.z; sdeg[3] += sv.w;
        ddeg[0] += dv.x; ddeg[1] += dv.y; ddeg[2] += dv.z; ddeg[3] += dv.w;
    }
    int pdeg[4];
#pragma unroll
    for (int j = 0; j < 4; j++) {
        int idx = t * 4 + j;
        int vs = sdeg[j]; if (vs < 1) vs = 1;
        rs_s[g * PP + idx] = rsqrtf((float)vs);
        int vd = ddeg[j]; if (vd < 1) vd = 1;
        rsd[g * PP + idx]  = rsqrtf((float)vd);
        pdeg[j] = (ddeg[j] + 3) & ~3;           // padded to multiple of 4
        degd[g * PP + idx] = pdeg[j];           // agg loops run over padded count
    }
    partial[t] = pdeg[0] + pdeg[1] + pdeg[2] + pdeg[3];
    __syncthreads();
    for (int off = 1; off < 1024; off <<= 1) {
        int v = partial[t];
        int add = (t >= off) ? partial[t - off] : 0;
        __syncthreads();
        partial[t] = v + add;
        __syncthreads();
    }
    int run = (t == 0) ? 0 : partial[t - 1];
#pragma unroll
    for (int j = 0; j < 4; j++) {
        int idx = t * 4 + j;
        offs[g * PP + idx] = g * CAP + run;
        int nb = run;                           // true edges placed at segment start
        for (int c = 0; c < 8; c++) {
            size_t hidx = (size_t)(g * 8 + c) * 4096 + idx;
            int v = dhist[hidx];
            dhist[hidx] = nb;                   // per-chunk cursor base (graph-relative)
            nb += v;
        }
        run += pdeg[j];                         // pad region stays zero
    }
}

// ---------------- build phase C: counting-sort placement ----------------
__global__ __launch_bounds__(1024) void k_place(const uint2* __restrict__ recs,
                                                const int* __restrict__ gcur,
                                                const int* __restrict__ dhist,
                                                const float* __restrict__ rs_s,
                                                unsigned* __restrict__ csr2) {
    __shared__ int cur[4096];
    __shared__ float rss[4096];
    int t = threadIdx.x;
    int g = blockIdx.x >> 3, c = blockIdx.x & 7;
    int n = gcur[g * 16] - g * CAP;
    int lo = (n * c) >> 3, hi = (n * (c + 1)) >> 3;
    ((int4*)cur)[t] = ((const int4*)(dhist + (size_t)blockIdx.x * 4096))[t];
    ((float4*)rss)[t] = ((const float4*)(rs_s + (size_t)g * PP))[t];
    __syncthreads();
    const uint2* base = recs + (size_t)g * CAP;
    unsigned* cbase = csr2 + (size_t)g * CAP;
    for (int i = lo + t; i < hi; i += 1024) {
        uint2 r = base[i];
        int sl = r.x & 4095, dl = (r.x >> 12) & 4095;
        int pos = atomicAdd(&cur[dl], 1);
        float wf = __uint_as_float(r.y) * rss[sl];
        cbase[pos] = (unsigned)sl | ((unsigned)__half_as_ushort(__float2half(wf)) << 16);
    }
}

// ================= FUSED layer 1: aggregate (half-wave/node) -> LDS -> MFMA =================
__global__ __launch_bounds__(256) void k_aggemm1(const unsigned* __restrict__ fx,   // [NN*32]
                                                 const unsigned* __restrict__ csr2,
                                                 const int* __restrict__ offs,
                                                 const int* __restrict__ degd,
                                                 const float* __restrict__ rsd,
                                                 const short* __restrict__ PW,
                                                 unsigned short* __restrict__ C,
                                                 float* __restrict__ part) {
    constexpr int WP = 36;                       // padded row stride (words); 36%4==0
    __shared__ unsigned lds[64 * WP];            // 9.2 KB
    __shared__ float s1[HH], s2[HH];
    int t = threadIdx.x;
    if (t < HH) { s1[t] = 0.f; s2[t] = 0.f; }
    int bid = blockIdx.x;                        // 2048 blocks
    int xcd = bid & 7, idx = bid >> 3;           // idx 0..255
    int g = xcd * 4 + (idx >> 6);                // XCD x owns graphs 4x..4x+3
    int node0 = g * PP + (idx & 63) * 64;        // 64 nodes per block, one graph
    int lane = t & 63, wv = t >> 6;
    int half = lane >> 5, sl = lane & 31;
    const unsigned* hp = fx + (size_t)((unsigned)(g * PP) * 32) + sl;
    for (int p = 0; p < 8; p++) {                // 16 nodes per wave, 2 per pass
        int lr = wv * 16 + p * 2 + half;         // local row
        int v = node0 + lr;
        int o = offs[v], cnt = degd[v];          // cnt % 4 == 0
        float ax0 = 0.f, ay0 = 0.f, ax1 = 0.f, ay1 = 0.f;
        for (int i = 0; i < cnt; i += 4) {
            uint4 rr = *(const uint4*)(csr2 + o + i);
            unsigned g0 = hp[(rr.x & 4095) * 32];
            unsigned g1 = hp[(rr.y & 4095) * 32];
            unsigned g2 = hp[(rr.z & 4095) * 32];
            unsigned g3 = hp[(rr.w & 4095) * 32];
            float w0 = w16(rr.x), w1 = w16(rr.y), w2 = w16(rr.z), w3 = w16(rr.w);
            ax0 += w0 * bflo(g0); ay0 += w0 * bfhi(g0);
            ax1 += w1 * bflo(g1); ay1 += w1 * bfhi(g1);
            ax0 += w2 * bflo(g2); ay0 += w2 * bfhi(g2);
            ax1 += w3 * bflo(g3); ay1 += w3 * bfhi(g3);
        }
        float rd = rsd[v];
        lds[lr * WP + sl] = pack2bf((ax0 + ax1) * rd, (ay0 + ay1) * rd);
    }
    __syncthreads();
    // MFMA: wave wv -> local rows wv*16..+15, K=64
    int m = lane & 15, quad = lane >> 4;
    bf16x8 a[2];
#pragma unroll
    for (int kt = 0; kt < 2; kt++)
        a[kt] = *(const bf16x8*)&lds[(wv * 16 + m) * WP + kt * 16 + quad * 4];
#pragma unroll
    for (int nt = 0; nt < 8; nt++) {
        f32x4 acc = {0.f, 0.f, 0.f, 0.f};
#pragma unroll
        for (int kt = 0; kt < 2; kt++) {
            bf16x8 b = *(const bf16x8*)(PW + ((size_t)(kt * 8 + nt) * 64 + lane) * 8);
            acc = __builtin_amdgcn_mfma_f32_16x16x32_bf16(a[kt], b, acc, 0, 0, 0);
        }
        int col = nt * 16 + m;
        int r0 = node0 + wv * 16 + quad * 4;
        float ps = 0.f, pq = 0.f;
#pragma unroll
        for (int r = 0; r < 4; r++) {
            C[(size_t)(r0 + r) * HH + col] = (unsigned short)f2bf(acc[r]);
            ps += acc[r]; pq += acc[r] * acc[r];
        }
        atomicAdd(&s1[col], ps);
        atomicAdd(&s2[col], pq);
    }
    __syncthreads();
    if (t < HH) {
        part[bid * 256 + t]      = s1[t];
        part[bid * 256 + HH + t] = s2[t];
    }
}

// ================= FUSED layer 2: fp8 gather (half-wave/node, dual-node) -> LDS -> MFMA =================
__global__ __launch_bounds__(256) void k_aggemm2(const unsigned* __restrict__ f8,   // [NN*32] fp8 words
                                                 const unsigned* __restrict__ csr2,
                                                 const int* __restrict__ offs,
                                                 const int* __restrict__ degd,
                                                 const float* __restrict__ rsd,
                                                 const short* __restrict__ PW,
                                                 unsigned short* __restrict__ C,
                                                 float* __restrict__ part) {
    constexpr int WP = 68;                       // padded row stride (words); 68%4==0
    __shared__ unsigned lds[64 * WP];            // 17.4 KB
    __shared__ float s1[HH], s2[HH];
    int t = threadIdx.x;
    if (t < HH) { s1[t] = 0.f; s2[t] = 0.f; }
    int bid = blockIdx.x;                        // 2048 blocks
    int xcd = bid & 7, idx = bid >> 3;
    int g = xcd * 4 + (idx >> 6);
    int node0 = g * PP + (idx & 63) * 64;
    int lane = t & 63, wv = t >> 6;
    int half = lane >> 5, sl = lane & 31;
    // fp8 row = 32 words; lane sl covers feats 4sl..4sl+3; one gather = 2 edges (one per half)
    const unsigned* hp8 = f8 + (size_t)((unsigned)(g * PP)) * 32 + sl;
    for (int p = 0; p < 4; p++) {                // per pass: half-wave handles nodes va, va+1
        int va = node0 + wv * 16 + p * 4 + half * 2;
        int vb = va + 1;
        int oa = offs[va], ca = degd[va];        // counts % 4 == 0
        int ob = offs[vb], cb = degd[vb];
        float A0 = 0.f, A1 = 0.f, A2 = 0.f, A3 = 0.f;
        float B0 = 0.f, B1 = 0.f, B2 = 0.f, B3 = 0.f;
        int c0 = ca < cb ? ca : cb;
        int cm = ca < cb ? cb : ca;
        int i = 0;
        for (; i < c0; i += 4) {                 // dual-node: 8 gathers in flight
            uint4 ra = *(const uint4*)(csr2 + oa + i);
            uint4 rb = *(const uint4*)(csr2 + ob + i);
            unsigned qa0 = hp8[(ra.x & 4095) * 32];
            unsigned qa1 = hp8[(ra.y & 4095) * 32];
            unsigned qa2 = hp8[(ra.z & 4095) * 32];
            unsigned qa3 = hp8[(ra.w & 4095) * 32];
            unsigned qb0 = hp8[(rb.x & 4095) * 32];
            unsigned qb1 = hp8[(rb.y & 4095) * 32];
            unsigned qb2 = hp8[(rb.z & 4095) * 32];
            unsigned qb3 = hp8[(rb.w & 4095) * 32];
            {
                f32x2 lo = __builtin_amdgcn_cvt_pk_f32_fp8((int)qa0, false);
                f32x2 hi = __builtin_amdgcn_cvt_pk_f32_fp8((int)qa0, true);
                float w = w16(ra.x);
                A0 += w * lo.x; A1 += w * lo.y; A2 += w * hi.x; A3 += w * hi.y;
            }
            {
                f32x2 lo = __builtin_amdgcn_cvt_pk_f32_fp8((int)qa1, false);
                f32x2 hi = __builtin_amdgcn_cvt_pk_f32_fp8((int)qa1, true);
                float w = w16(ra.y);
                A0 += w * lo.x; A1 += w * lo.y; A2 += w * hi.x; A3 += w * hi.y;
            }
            {
                f32x2 lo = __builtin_amdgcn_cvt_pk_f32_fp8((int)qa2, false);
                f32x2 hi = __builtin_amdgcn_cvt_pk_f32_fp8((int)qa2, true);
                float w = w16(ra.z);
                A0 += w * lo.x; A1 += w * lo.y; A2 += w * hi.x; A3 += w * hi.y;
            }
            {
                f32x2 lo = __builtin_amdgcn_cvt_pk_f32_fp8((int)qa3, false);
                f32x2 hi = __builtin_amdgcn_cvt_pk_f32_fp8((int)qa3, true);
                float w = w16(ra.w);
                A0 += w * lo.x; A1 += w * lo.y; A2 += w * hi.x; A3 += w * hi.y;
            }
            {
                f32x2 lo = __builtin_amdgcn_cvt_pk_f32_fp8((int)qb0, false);
                f32x2 hi = __builtin_amdgcn_cvt_pk_f32_fp8((int)qb0, true);
                float w = w16(rb.x);
                B0 += w * lo.x; B1 += w * lo.y; B2 += w * hi.x; B3 += w * hi.y;
            }
            {
                f32x2 lo = __builtin_amdgcn_cvt_pk_f32_fp8((int)qb1, false);
                f32x2 hi = __builtin_amdgcn_cvt_pk_f32_fp8((int)qb1, true);
                float w = w16(rb.y);
                B0 += w * lo.x; B1 += w * lo.y; B2 += w * hi.x; B3 += w * hi.y;
            }
            {
                f32x2 lo = __builtin_amdgcn_cvt_pk_f32_fp8((int)qb2, false);
                f32x2 hi = __builtin_amdgcn_cvt_pk_f32_fp8((int)qb2, true);
                float w = w16(rb.z);
                B0 += w * lo.x; B1 += w * lo.y; B2 += w * hi.x; B3 += w * hi.y;
            }
            {
                f32x2 lo = __builtin_amdgcn_cvt_pk_f32_fp8((int)qb3, false);
                f32x2 hi = __builtin_amdgcn_cvt_pk_f32_fp8((int)qb3, true);
                float w = w16(rb.w);
                B0 += w * lo.x; B1 += w * lo.y; B2 += w * hi.x; B3 += w * hi.y;
            }
        }
        if (i < cm) {                            // remainder: one node (per half) has extra
            int ot = (ca > cb) ? oa : ob;
            float E0 = 0.f, E1 = 0.f, E2 = 0.f, E3 = 0.f;
            for (; i < cm; i += 4) {
                uint4 rr = *(const uint4*)(csr2 + ot + i);
                unsigned q0 = hp8[(rr.x & 4095) * 32];
                unsigned q1 = hp8[(rr.y & 4095) * 32];
                unsigned q2 = hp8[(rr.z & 4095) * 32];
                unsigned q3 = hp8[(rr.w & 4095) * 32];
                {
                    f32x2 lo = __builtin_amdgcn_cvt_pk_f32_fp8((int)q0, false);
                    f32x2 hi = __builtin_amdgcn_cvt_pk_f32_fp8((int)q0, true);
                    float w = w16(rr.x);
                    E0 += w * lo.x; E1 += w * lo.y; E2 += w * hi.x; E3 += w * hi.y;
                }
                {
                    f32x2 lo = __builtin_amdgcn_cvt_pk_f32_fp8((int)q1, false);
                    f32x2 hi = __builtin_amdgcn_cvt_pk_f32_fp8((int)q1, true);
                    float w = w16(rr.y);
                    E0 += w * lo.x; E1 += w * lo.y; E2 += w * hi.x; E3 += w * hi.y;
                }
                {
                    f32x2 lo = __builtin_amdgcn_cvt_pk_f32_fp8((int)q2, false);
                    f32x2 hi = __builtin_amdgcn_cvt_pk_f32_fp8((int)q2, true);
                    float w = w16(rr.z);
                    E0 += w * lo.x; E1 += w * lo.y; E2 += w * hi.x; E3 += w * hi.y;
                }
                {
                    f32x2 lo = __builtin_amdgcn_cvt_pk_f32_fp8((int)q3, false);
                    f32x2 hi = __builtin_amdgcn_cvt_pk_f32_fp8((int)q3, true);
                    float w = w16(rr.w);
                    E0 += w * lo.x; E1 += w * lo.y; E2 += w * hi.x; E3 += w * hi.y;
                }
            }
            if (ca > cb) { A0 += E0; A1 += E1; A2 += E2; A3 += E3; }
            else         { B0 += E0; B1 += E1; B2 += E2; B3 += E3; }
        }
        float rda = rsd[va], rdb = rsd[vb];
        int lrA = wv * 16 + p * 4 + half * 2;
        *(uint2*)&lds[lrA * WP + sl * 2] =
            make_uint2(pack2bf(A0 * rda, A1 * rda), pack2bf(A2 * rda, A3 * rda));
        *(uint2*)&lds[(lrA + 1) * WP + sl * 2] =
            make_uint2(pack2bf(B0 * rdb, B1 * rdb), pack2bf(B2 * rdb, B3 * rdb));
    }
    __syncthreads();
    // MFMA: wave wv -> local rows wv*16..+15, K=128
    int m = lane & 15, quad = lane >> 4;
    bf16x8 a[4];
#pragma unroll
    for (int kt = 0; kt < 4; kt++)
        a[kt] = *(const bf16x8*)&lds[(wv * 16 + m) * WP + kt * 16 + quad * 4];
#pragma unroll
    for (int nt = 0; nt < 8; nt++) {
        f32x4 acc = {0.f, 0.f, 0.f, 0.f};
#pragma unroll
        for (int kt = 0; kt < 4; kt++) {
            bf16x8 b = *(const bf16x8*)(PW + ((size_t)(kt * 8 + nt) * 64 + lane) * 8);
            acc = __builtin_amdgcn_mfma_f32_16x16x32_bf16(a[kt], b, acc, 0, 0, 0);
        }
        int col = nt * 16 + m;
        int r0 = node0 + wv * 16 + quad * 4;
        float ps = 0.f, pq = 0.f;
#pragma unroll
        for (int r = 0; r < 4; r++) {
            C[(size_t)(r0 + r) * HH + col] = (unsigned short)f2bf(acc[r]);
            ps += acc[r]; pq += acc[r] * acc[r];
        }
        atomicAdd(&s1[col], ps);
        atomicAdd(&s2[col], pq);
    }
    __syncthreads();
    if (t < HH) {
        part[bid * 256 + t]      = s1[t];
        part[bid * 256 + HH + t] = s2[t];
    }
}

// ---------------- stage-1 reduction of gemm partials ----------------
__global__ __launch_bounds__(256) void k_red(const float* __restrict__ part,
                                             float* __restrict__ pb) {
    int t = threadIdx.x, b = blockIdx.x;        // 64 blocks
    float s = 0.f;
    for (int r = 0; r < 32; r++) s += part[(size_t)(b * 32 + r) * 256 + t];
    pb[b * 256 + t] = s;
}

// ---------------- reduce + norm coefficients ----------------
__global__ void k_coef(const float* __restrict__ pb, const float* __restrict__ gamma,
                       const float* __restrict__ beta, const float* __restrict__ alpha,
                       float* __restrict__ ab) {
    int t = threadIdx.x;                         // 256 threads
    float s = 0.f;
    for (int b = 0; b < 64; b++) s += pb[b * 256 + t];
    __shared__ float sh[256];
    sh[t] = s;
    __syncthreads();
    if (t < 128) {
        float mu = sh[t] * (1.f / NN);
        float e2 = sh[128 + t] * (1.f / NN);
        float al = alpha[t];
        float var = e2 - (2.f * al - al * al) * mu * mu;
        float a = rsqrtf(var + EPSV) * gamma[t];
        ab[t] = a;
        ab[HH + t] = beta[t] - al * mu * a;
    }
}

// ---------------- fused norm + leaky-relu (+fp8 h1 emit) + per-graph readout ----------------
template <bool WRITE>
__global__ __launch_bounds__(256) void k_normro(const unsigned* __restrict__ h,  // bf16 pairs
                                                const float* __restrict__ ab,
                                                float* __restrict__ racc,
                                                unsigned short* __restrict__ f8) {
    int fp = threadIdx.x & 63;                   // feature pair
    int q  = threadIdx.x >> 6;                   // 0..3
    int node0 = blockIdx.x * 64;                 // one graph per block
    int g = node0 / PP;
    float a0 = ab[2 * fp], a1 = ab[2 * fp + 1];
    float b0 = ab[HH + 2 * fp], b1 = ab[HH + 2 * fp + 1];
    float s0 = 0.f, s1 = 0.f;
    for (int i = q; i < 64; i += 4) {
        size_t idx = (size_t)(node0 + i) * 64 + fp;
        unsigned v = h[idx];
        float x0 = fmaf(a0, bflo(v), b0); x0 = x0 > 0.f ? x0 : SLOPEV * x0;
        float x1 = fmaf(a1, bfhi(v), b1); x1 = x1 > 0.f ? x1 : SLOPEV * x1;
        if (WRITE) f8[idx] = (unsigned short)__builtin_amdgcn_cvt_pk_fp8_f32(x0, x1, 0, false);
        s0 += x0; s1 += x1;
    }
    __shared__ float sh[512];
    sh[threadIdx.x] = s0;
    sh[256 + threadIdx.x] = s1;
    __syncthreads();
    if (q == 0) {
        float t0 = s0 + sh[64 + fp] + sh[128 + fp] + sh[192 + fp];
        float t1 = s1 + sh[256 + 64 + fp] + sh[256 + 128 + fp] + sh[256 + 192 + fp];
        atomicAdd(&racc[g * HH + 2 * fp],     t0);
        atomicAdd(&racc[g * HH + 2 * fp + 1], t1);
    }
}

// ---------------- final head ----------------
__global__ void k_final(const float* __restrict__ racc1, const float* __restrict__ racc2,
                        const float* __restrict__ Wc, float* __restrict__ out) {
    int t = threadIdx.x;                         // 512 = 32*16
    int b = t >> 4, o = t & 15;
    float acc = 0.f;
    for (int f = 0; f < HH; f++) acc += racc1[b * HH + f] * Wc[o * (2 * HH) + f];
    for (int f = 0; f < HH; f++) acc += racc2[b * HH + f] * Wc[o * (2 * HH) + HH + f];
    out[t] = acc * (1.f / PP);
}

extern "C" void kernel_launch(void* const* d_in, const int* in_sizes, int n_in,
                              void* d_out, int out_size, void* d_ws, size_t ws_size,
                              hipStream_t stream) {
    const float* features = (const float*)d_in[0];
    const float* ew       = (const float*)d_in[1];
    const int*   src      = (const int*)d_in[2];
    const int*   dst      = (const int*)d_in[3];
    const float* W1       = (const float*)d_in[4];
    const float* W2       = (const float*)d_in[5];
    const float* Wc       = (const float*)d_in[6];
    const float* gamma1   = (const float*)d_in[7];
    const float* beta1    = (const float*)d_in[8];
    const float* alpha1   = (const float*)d_in[9];
    const float* gamma2   = (const float*)d_in[10];
    const float* beta2    = (const float*)d_in[11];
    const float* alpha2   = (const float*)d_in[12];
    float* out = (float*)d_out;

    char* w = (char*)d_ws;
    // misc block [0, 1 MB)
    int*    gcur   = (int*)(w + 0);                         // 32 * 16 ints
    float*  racc1  = (float*)(w + (16u << 10));             // 16 KB
    float*  racc2  = (float*)(w + (32u << 10));             // contiguous with racc1
    float*  ab1    = (float*)(w + (48u << 10));
    float*  ab2    = (float*)(w + (52u << 10));
    unsigned short* pw1 = (unsigned short*)(w + (64u << 10));   // 16 KB
    unsigned short* pw2 = (unsigned short*)(w + (80u << 10));   // 32 KB
    float*  pb     = (float*)(w + (128u << 10));            // 64 KB
    // arrays
    float*  rs_s   = (float*)(w + (1024u << 10));           // 512 KB
    float*  rsd    = (float*)(w + (1536u << 10));           // 512 KB
    int*    degd   = (int*)(w + (2048u << 10));             // 512 KB
    int*    offs   = (int*)(w + (2560u << 10));             // 512 KB
    float*  part   = (float*)(w + (3u << 20));              // 2 MB: 3..5
    int*    shist  = (int*)(w + (5u << 20));                // 4 MB: 5..9
    int*    dhist  = (int*)(w + (9u << 20));                // 4 MB: 9..13
    unsigned* csr2 = (unsigned*)(w + (13u << 20));          // 10 MB: 13..23
    unsigned* mbuf = (unsigned*)(w + (23u << 20));          // 32 MB: 23..55 (h2pre)
    unsigned* hbuf = (unsigned*)(w + (55u << 20));          // 32 MB: 55..87 (h1pre)
    uint2*    recs = (uint2*)(w + (87u << 20));             // 20 MB: 87..107
    unsigned* fx   = (unsigned*)(w + (107u << 20));         // 16 MB: 107..123
    unsigned* f8buf= (unsigned*)(w + (123u << 20));         // 16 MB: 123..139 (h1 fp8)

    // prep (cvt + init + packw + csr2 zero, fused)
    k_prep<<<18957, 256, 0, stream>>>(features, fx, W1, pw1, W2, pw2, gcur, racc1, csr2);

    // CSR build
    k_part<<<EE / 4096, 256, 0, stream>>>(src, dst, ew, gcur, recs);
    k_hist<<<BG * 8, 1024, 0, stream>>>(recs, gcur, shist, dhist);
    k_offs<<<BG, 1024, 0, stream>>>(shist, dhist, rs_s, rsd, degd, offs);
    k_place<<<BG * 8, 1024, 0, stream>>>(recs, gcur, dhist, rs_s, csr2);

    // ---- layer 1 (fused agg+gemm) ----
    k_aggemm1<<<NN / 64, 256, 0, stream>>>(fx, csr2, offs, degd, rsd,
                                           (const short*)pw1, (unsigned short*)hbuf, part);
    k_red<<<64, 256, 0, stream>>>(part, pb);
    k_coef<<<1, 256, 0, stream>>>(pb, gamma1, beta1, alpha1, ab1);
    k_normro<true><<<NN / 64, 256, 0, stream>>>(hbuf, ab1, racc1, (unsigned short*)f8buf);

    // ---- layer 2 (fused agg+gemm; gathers fp8 h1, writes mbuf) ----
    k_aggemm2<<<NN / 64, 256, 0, stream>>>(f8buf, csr2, offs, degd, rsd,
                                           (const short*)pw2, (unsigned short*)mbuf, part);
    k_red<<<64, 256, 0, stream>>>(part, pb);
    k_coef<<<1, 256, 0, stream>>>(pb, gamma2, beta2, alpha2, ab2);
    k_normro<false><<<NN / 64, 256, 0, stream>>>(mbuf, ab2, racc2, nullptr);

    // ---- head ----
    k_final<<<1, 512, 0, stream>>>(racc1, racc2, Wc, out);
}

// Round 9
// 353.620 us; speedup vs baseline: 1.2604x; 1.0537x over previous
//
#include <hip/hip_runtime.h>
#include <hip/hip_fp16.h>

constexpr int NN   = 131072;   // total nodes
constexpr int PP   = 4096;     // nodes per graph
constexpr int BG   = 32;       // graphs
constexpr int EE   = 2097152;  // edges
constexpr int IND  = 64;
constexpr int HH   = 128;
constexpr int CAP  = 81920;    // per-graph slot capacity (65536 mean + pad4 + slack)
constexpr float EPSV   = 1e-5f;
constexpr float SLOPEV = 0.01f;

typedef short bf16x8 __attribute__((ext_vector_type(8)));
typedef float f32x4  __attribute__((ext_vector_type(4)));
typedef float f32x2  __attribute__((ext_vector_type(2)));

__device__ __forceinline__ unsigned f2bf(float f) {
    unsigned u = __float_as_uint(f);
    return (u + 0x7FFFu + ((u >> 16) & 1u)) >> 16;      // RNE
}
__device__ __forceinline__ unsigned pack2bf(float lo, float hi) {
    return f2bf(lo) | (f2bf(hi) << 16);
}
__device__ __forceinline__ float bflo(unsigned p) { return __uint_as_float(p << 16); }
__device__ __forceinline__ float bfhi(unsigned p) { return __uint_as_float(p & 0xFFFF0000u); }
__device__ __forceinline__ float w16(unsigned r) {
    return __half2float(__ushort_as_half((unsigned short)(r >> 16)));
}

// ---------------- W -> MFMA B-fragment prepack (device body) ----------------
template <int K>
__device__ __forceinline__ void packw_body(const float* __restrict__ W,
                                           unsigned short* __restrict__ pw, int t) {
    if (t >= K * 16) return;
    int lane = t & 63, nt = (t >> 6) & 7, kt = t >> 9;
    int kbase = kt * 32 + ((lane >> 4) & 3) * 8;
    int col   = nt * 16 + (lane & 15);
    for (int j = 0; j < 8; j++)
        pw[t * 8 + j] = (unsigned short)f2bf(W[(kbase + j) * HH + col]);
}

// ---------------- fused prep: feature->fp8 cvt + init + weight prepack + csr2 zero ----------------
__global__ __launch_bounds__(256) void k_prep(const float* __restrict__ features,
                                              unsigned* __restrict__ f8x,
                                              const float* __restrict__ W1,
                                              unsigned short* __restrict__ pw1,
                                              const float* __restrict__ W2,
                                              unsigned short* __restrict__ pw2,
                                              int* __restrict__ gcur,
                                              float* __restrict__ racc,
                                              unsigned* __restrict__ csr2) {
    int b = blockIdx.x, t = threadIdx.x;
    if (b < 8192) {                     // fp8 convert: NN*16 = 8192*256 words
        int i = b * 256 + t;
        float4 v = ((const float4*)features)[i];
        int w0 = __builtin_amdgcn_cvt_pk_fp8_f32(v.x, v.y, 0, false);
        int w1 = __builtin_amdgcn_cvt_pk_fp8_f32(v.z, v.w, w0, true);
        f8x[i] = (unsigned)w1;
        return;
    }
    if (b == 8192) {                    // init cursors + readout accumulators
        if (t < BG) gcur[t * 16] = t * CAP;
        for (int i = t; i < 2 * BG * HH; i += 256) racc[i] = 0.f;
        return;
    }
    if (b < 8197) { packw_body<64>(W1, pw1, (b - 8193) * 256 + t); return; }
    if (b < 8205) { packw_body<128>(W2, pw2, (b - 8197) * 256 + t); return; }
    // zero csr2 pad region: BG*CAP words = 163840 uint4 = 2560 blocks
    ((uint4*)csr2)[(b - 8205) * 256 + t] = make_uint4(0, 0, 0, 0);
}

// ---------------- pass 1: 32-way partition of edges by graph ----------------
__global__ __launch_bounds__(256) void k_part(const int* __restrict__ src,
                                              const int* __restrict__ dst,
                                              const float* __restrict__ ew,
                                              int* __restrict__ gcur,
                                              uint2* __restrict__ recs) {
    __shared__ int cnt[32];
    __shared__ int start[32];
    __shared__ int gbase[32];
    __shared__ uint2 stage[4096];
    int t = threadIdx.x;
    int ebase = blockIdx.x * 4096;
    if (t < 32) cnt[t] = 0;
    __syncthreads();
    int es[16]; int ed[16]; float ev[16];
#pragma unroll
    for (int k = 0; k < 16; k++) {
        int e = ebase + k * 256 + t;
        es[k] = src[e]; ed[k] = dst[e]; ev[k] = ew[e];
        atomicAdd(&cnt[es[k] >> 12], 1);
    }
    __syncthreads();
    if (t == 0) {
        int run = 0;
        for (int g = 0; g < 32; g++) { start[g] = run; run += cnt[g]; }
    }
    __syncthreads();
    if (t < 32) {
        gbase[t] = atomicAdd(&gcur[t * 16], cnt[t]);
        cnt[t] = start[t];                      // becomes cursor
    }
    __syncthreads();
#pragma unroll
    for (int k = 0; k < 16; k++) {
        int g = es[k] >> 12;
        int pos = atomicAdd(&cnt[g], 1);
        stage[pos] = make_uint2((unsigned)(es[k] & 4095) | ((unsigned)(ed[k] & 4095) << 12) |
                                ((unsigned)g << 24), __float_as_uint(ev[k]));
    }
    __syncthreads();
    for (int i = t; i < 4096; i += 256) {
        uint2 r = stage[i];
        int g = r.x >> 24;
        recs[gbase[g] + (i - start[g])] = r;
    }
}

// ---------------- build phase A: per-(graph,chunk) histograms ----------------
__global__ __launch_bounds__(1024) void k_hist(const uint2* __restrict__ recs,
                                               const int* __restrict__ gcur,
                                               int* __restrict__ shist,
                                               int* __restrict__ dhist) {
    __shared__ int hs[4096];
    __shared__ int hd[4096];
    int t = threadIdx.x;
    int g = blockIdx.x >> 3, c = blockIdx.x & 7;
    int n = gcur[g * 16] - g * CAP;
    int lo = (n * c) >> 3, hi = (n * (c + 1)) >> 3;
    ((int4*)hs)[t] = make_int4(0, 0, 0, 0);
    ((int4*)hd)[t] = make_int4(0, 0, 0, 0);
    __syncthreads();
    const uint2* base = recs + (size_t)g * CAP;
    for (int i = lo + t; i < hi; i += 1024) {
        unsigned x = base[i].x;
        atomicAdd(&hs[x & 4095], 1);
        atomicAdd(&hd[(x >> 12) & 4095], 1);
    }
    __syncthreads();
    ((int4*)(shist + (size_t)blockIdx.x * 4096))[t] = ((int4*)hs)[t];
    ((int4*)(dhist + (size_t)blockIdx.x * 4096))[t] = ((int4*)hd)[t];
}

// ---------------- build phase B: degrees, rsqrt, padded offsets, chunk cursor bases ----------------
__global__ __launch_bounds__(1024) void k_offs(int* __restrict__ shist,
                                               int* __restrict__ dhist,
                                               float* __restrict__ rs_s,
                                               float* __restrict__ rsd,
                                               int* __restrict__ degd,
                                               int* __restrict__ offs) {
    __shared__ int partial[1024];
    int t = threadIdx.x, g = blockIdx.x;
    int sdeg[4] = {0, 0, 0, 0}, ddeg[4] = {0, 0, 0, 0};
#pragma unroll
    for (int c = 0; c < 8; c++) {
        int4 sv = ((const int4*)(shist + (size_t)(g * 8 + c) * 4096))[t];
        int4 dv = ((const int4*)(dhist + (size_t)(g * 8 + c) * 4096))[t];
        sdeg[0] += sv.x; sdeg[1] += sv.y; sdeg[2] += sv.z; sdeg[3] += sv.w;
        ddeg[0] += dv.x; ddeg[1] += dv.y; ddeg[2] += dv.z; ddeg[3] += dv.w;
    }
    int pdeg[4];
#pragma unroll
    for (int j = 0; j < 4; j++) {
        int idx = t * 4 + j;
        int vs = sdeg[j]; if (vs < 1) vs = 1;
        rs_s[g * PP + idx] = rsqrtf((float)vs);
        int vd = ddeg[j]; if (vd < 1) vd = 1;
        rsd[g * PP + idx]  = rsqrtf((float)vd);
        pdeg[j] = (ddeg[j] + 3) & ~3;           // padded to multiple of 4
        degd[g * PP + idx] = pdeg[j];           // agg loops run over padded count
    }
    partial[t] = pdeg[0] + pdeg[1] + pdeg[2] + pdeg[3];
    __syncthreads();
    for (int off = 1; off < 1024; off <<= 1) {
        int v = partial[t];
        int add = (t >= off) ? partial[t - off] : 0;
        __syncthreads();
        partial[t] = v + add;
        __syncthreads();
    }
    int run = (t == 0) ? 0 : partial[t - 1];
#pragma unroll
    for (int j = 0; j < 4; j++) {
        int idx = t * 4 + j;
        offs[g * PP + idx] = g * CAP + run;
        int nb = run;                           // true edges placed at segment start
        for (int c = 0; c < 8; c++) {
            size_t hidx = (size_t)(g * 8 + c) * 4096 + idx;
            int v = dhist[hidx];
            dhist[hidx] = nb;                   // per-chunk cursor base (graph-relative)
            nb += v;
        }
        run += pdeg[j];                         // pad region stays zero
    }
}

// ---------------- build phase C: counting-sort placement ----------------
__global__ __launch_bounds__(1024) void k_place(const uint2* __restrict__ recs,
                                                const int* __restrict__ gcur,
                                                const int* __restrict__ dhist,
                                                const float* __restrict__ rs_s,
                                                unsigned* __restrict__ csr2) {
    __shared__ int cur[4096];
    __shared__ float rss[4096];
    int t = threadIdx.x;
    int g = blockIdx.x >> 3, c = blockIdx.x & 7;
    int n = gcur[g * 16] - g * CAP;
    int lo = (n * c) >> 3, hi = (n * (c + 1)) >> 3;
    ((int4*)cur)[t] = ((const int4*)(dhist + (size_t)blockIdx.x * 4096))[t];
    ((float4*)rss)[t] = ((const float4*)(rs_s + (size_t)g * PP))[t];
    __syncthreads();
    const uint2* base = recs + (size_t)g * CAP;
    unsigned* cbase = csr2 + (size_t)g * CAP;
    for (int i = lo + t; i < hi; i += 1024) {
        uint2 r = base[i];
        int sl = r.x & 4095, dl = (r.x >> 12) & 4095;
        int pos = atomicAdd(&cur[dl], 1);
        float wf = __uint_as_float(r.y) * rss[sl];
        cbase[pos] = (unsigned)sl | ((unsigned)__half_as_ushort(__float2half(wf)) << 16);
    }
}

// ================= FUSED layer 1: fp8 gather (quarter-wave/node, dual-node) -> LDS -> MFMA =================
__global__ __launch_bounds__(256) void k_aggemm1(const unsigned* __restrict__ f8x,  // [NN*16] fp8 words
                                                 const unsigned* __restrict__ csr2,
                                                 const int* __restrict__ offs,
                                                 const int* __restrict__ degd,
                                                 const float* __restrict__ rsd,
                                                 const short* __restrict__ PW,
                                                 unsigned short* __restrict__ C,
                                                 float* __restrict__ part) {
    constexpr int WP = 36;                       // padded row stride (words); 144 B, 16B-aligned
    __shared__ unsigned lds[64 * WP];            // 9.2 KB
    __shared__ float s1[HH], s2[HH];
    int t = threadIdx.x;
    if (t < HH) { s1[t] = 0.f; s2[t] = 0.f; }
    int bid = blockIdx.x;                        // 2048 blocks
    int xcd = bid & 7, idx = bid >> 3;           // idx 0..255
    int g = xcd * 4 + (idx >> 6);                // XCD x owns graphs 4x..4x+3
    int node0 = g * PP + (idx & 63) * 64;        // 64 nodes per block, one graph
    int lane = t & 63, wv = t >> 6;
    int q = lane >> 4, ql = lane & 15;           // quarter-wave covers a 16-word fp8 row
    const unsigned* hp8 = f8x + (size_t)((unsigned)(g * PP)) * 16 + ql;
    for (int p = 0; p < 2; p++) {                // per pass: quarter handles nodes va, va+1
        int lrA = wv * 16 + p * 8 + q * 2;       // local row
        int va = node0 + lrA, vb = va + 1;
        int oa = offs[va], ca = degd[va];        // counts % 4 == 0
        int ob = offs[vb], cb = degd[vb];
        float A0 = 0.f, A1 = 0.f, A2 = 0.f, A3 = 0.f;
        float B0 = 0.f, B1 = 0.f, B2 = 0.f, B3 = 0.f;
        int c0 = ca < cb ? ca : cb;
        int cm = ca < cb ? cb : ca;
        int i = 0;
        for (; i < c0; i += 4) {                 // dual-node: 8 gathers in flight
            uint4 ra = *(const uint4*)(csr2 + oa + i);
            uint4 rb = *(const uint4*)(csr2 + ob + i);
            unsigned qa0 = hp8[(ra.x & 4095) * 16];
            unsigned qa1 = hp8[(ra.y & 4095) * 16];
            unsigned qa2 = hp8[(ra.z & 4095) * 16];
            unsigned qa3 = hp8[(ra.w & 4095) * 16];
            unsigned qb0 = hp8[(rb.x & 4095) * 16];
            unsigned qb1 = hp8[(rb.y & 4095) * 16];
            unsigned qb2 = hp8[(rb.z & 4095) * 16];
            unsigned qb3 = hp8[(rb.w & 4095) * 16];
            {
                f32x2 lo = __builtin_amdgcn_cvt_pk_f32_fp8((int)qa0, false);
                f32x2 hi = __builtin_amdgcn_cvt_pk_f32_fp8((int)qa0, true);
                float w = w16(ra.x);
                A0 += w * lo.x; A1 += w * lo.y; A2 += w * hi.x; A3 += w * hi.y;
            }
            {
                f32x2 lo = __builtin_amdgcn_cvt_pk_f32_fp8((int)qa1, false);
                f32x2 hi = __builtin_amdgcn_cvt_pk_f32_fp8((int)qa1, true);
                float w = w16(ra.y);
                A0 += w * lo.x; A1 += w * lo.y; A2 += w * hi.x; A3 += w * hi.y;
            }
            {
                f32x2 lo = __builtin_amdgcn_cvt_pk_f32_fp8((int)qa2, false);
                f32x2 hi = __builtin_amdgcn_cvt_pk_f32_fp8((int)qa2, true);
                float w = w16(ra.z);
                A0 += w * lo.x; A1 += w * lo.y; A2 += w * hi.x; A3 += w * hi.y;
            }
            {
                f32x2 lo = __builtin_amdgcn_cvt_pk_f32_fp8((int)qa3, false);
                f32x2 hi = __builtin_amdgcn_cvt_pk_f32_fp8((int)qa3, true);
                float w = w16(ra.w);
                A0 += w * lo.x; A1 += w * lo.y; A2 += w * hi.x; A3 += w * hi.y;
            }
            {
                f32x2 lo = __builtin_amdgcn_cvt_pk_f32_fp8((int)qb0, false);
                f32x2 hi = __builtin_amdgcn_cvt_pk_f32_fp8((int)qb0, true);
                float w = w16(rb.x);
                B0 += w * lo.x; B1 += w * lo.y; B2 += w * hi.x; B3 += w * hi.y;
            }
            {
                f32x2 lo = __builtin_amdgcn_cvt_pk_f32_fp8((int)qb1, false);
                f32x2 hi = __builtin_amdgcn_cvt_pk_f32_fp8((int)qb1, true);
                float w = w16(rb.y);
                B0 += w * lo.x; B1 += w * lo.y; B2 += w * hi.x; B3 += w * hi.y;
            }
            {
                f32x2 lo = __builtin_amdgcn_cvt_pk_f32_fp8((int)qb2, false);
                f32x2 hi = __builtin_amdgcn_cvt_pk_f32_fp8((int)qb2, true);
                float w = w16(rb.z);
                B0 += w * lo.x; B1 += w * lo.y; B2 += w * hi.x; B3 += w * hi.y;
            }
            {
                f32x2 lo = __builtin_amdgcn_cvt_pk_f32_fp8((int)qb3, false);
                f32x2 hi = __builtin_amdgcn_cvt_pk_f32_fp8((int)qb3, true);
                float w = w16(rb.w);
                B0 += w * lo.x; B1 += w * lo.y; B2 += w * hi.x; B3 += w * hi.y;
            }
        }
        if (i < cm) {                            // remainder: one node has extra
            int ot = (ca > cb) ? oa : ob;
            float E0 = 0.f, E1 = 0.f, E2 = 0.f, E3 = 0.f;
            for (; i < cm; i += 4) {
                uint4 rr = *(const uint4*)(csr2 + ot + i);
                unsigned q0 = hp8[(rr.x & 4095) * 16];
                unsigned q1 = hp8[(rr.y & 4095) * 16];
                unsigned q2 = hp8[(rr.z & 4095) * 16];
                unsigned q3 = hp8[(rr.w & 4095) * 16];
                {
                    f32x2 lo = __builtin_amdgcn_cvt_pk_f32_fp8((int)q0, false);
                    f32x2 hi = __builtin_amdgcn_cvt_pk_f32_fp8((int)q0, true);
                    float w = w16(rr.x);
                    E0 += w * lo.x; E1 += w * lo.y; E2 += w * hi.x; E3 += w * hi.y;
                }
                {
                    f32x2 lo = __builtin_amdgcn_cvt_pk_f32_fp8((int)q1, false);
                    f32x2 hi = __builtin_amdgcn_cvt_pk_f32_fp8((int)q1, true);
                    float w = w16(rr.y);
                    E0 += w * lo.x; E1 += w * lo.y; E2 += w * hi.x; E3 += w * hi.y;
                }
                {
                    f32x2 lo = __builtin_amdgcn_cvt_pk_f32_fp8((int)q2, false);
                    f32x2 hi = __builtin_amdgcn_cvt_pk_f32_fp8((int)q2, true);
                    float w = w16(rr.z);
                    E0 += w * lo.x; E1 += w * lo.y; E2 += w * hi.x; E3 += w * hi.y;
                }
                {
                    f32x2 lo = __builtin_amdgcn_cvt_pk_f32_fp8((int)q3, false);
                    f32x2 hi = __builtin_amdgcn_cvt_pk_f32_fp8((int)q3, true);
                    float w = w16(rr.w);
                    E0 += w * lo.x; E1 += w * lo.y; E2 += w * hi.x; E3 += w * hi.y;
                }
            }
            if (ca > cb) { A0 += E0; A1 += E1; A2 += E2; A3 += E3; }
            else         { B0 += E0; B1 += E1; B2 += E2; B3 += E3; }
        }
        float rda = rsd[va], rdb = rsd[vb];
        *(uint2*)&lds[lrA * WP + ql * 2] =
            make_uint2(pack2bf(A0 * rda, A1 * rda), pack2bf(A2 * rda, A3 * rda));
        *(uint2*)&lds[(lrA + 1) * WP + ql * 2] =
            make_uint2(pack2bf(B0 * rdb, B1 * rdb), pack2bf(B2 * rdb, B3 * rdb));
    }
    __syncthreads();
    // MFMA: wave wv -> local rows wv*16..+15, K=64
    int m = lane & 15, quad = lane >> 4;
    bf16x8 a[2];
#pragma unroll
    for (int kt = 0; kt < 2; kt++)
        a[kt] = *(const bf16x8*)&lds[(wv * 16 + m) * WP + kt * 16 + quad * 4];
#pragma unroll
    for (int nt = 0; nt < 8; nt++) {
        f32x4 acc = {0.f, 0.f, 0.f, 0.f};
#pragma unroll
        for (int kt = 0; kt < 2; kt++) {
            bf16x8 b = *(const bf16x8*)(PW + ((size_t)(kt * 8 + nt) * 64 + lane) * 8);
            acc = __builtin_amdgcn_mfma_f32_16x16x32_bf16(a[kt], b, acc, 0, 0, 0);
        }
        int col = nt * 16 + m;
        int r0 = node0 + wv * 16 + quad * 4;
        float ps = 0.f, pq = 0.f;
#pragma unroll
        for (int r = 0; r < 4; r++) {
            C[(size_t)(r0 + r) * HH + col] = (unsigned short)f2bf(acc[r]);
            ps += acc[r]; pq += acc[r] * acc[r];
        }
        atomicAdd(&s1[col], ps);
        atomicAdd(&s2[col], pq);
    }
    __syncthreads();
    if (t < HH) {
        part[bid * 256 + t]      = s1[t];
        part[bid * 256 + HH + t] = s2[t];
    }
}

// ================= FUSED layer 2: fp8 gather (half-wave/node, dual-node) -> LDS -> MFMA =================
__global__ __launch_bounds__(256) void k_aggemm2(const unsigned* __restrict__ f8,   // [NN*32] fp8 words
                                                 const unsigned* __restrict__ csr2,
                                                 const int* __restrict__ offs,
                                                 const int* __restrict__ degd,
                                                 const float* __restrict__ rsd,
                                                 const short* __restrict__ PW,
                                                 unsigned short* __restrict__ C,
                                                 float* __restrict__ part) {
    constexpr int WP = 68;                       // padded row stride (words); 68%4==0
    __shared__ unsigned lds[64 * WP];            // 17.4 KB
    __shared__ float s1[HH], s2[HH];
    int t = threadIdx.x;
    if (t < HH) { s1[t] = 0.f; s2[t] = 0.f; }
    int bid = blockIdx.x;                        // 2048 blocks
    int xcd = bid & 7, idx = bid >> 3;
    int g = xcd * 4 + (idx >> 6);
    int node0 = g * PP + (idx & 63) * 64;
    int lane = t & 63, wv = t >> 6;
    int half = lane >> 5, sl = lane & 31;
    // fp8 row = 32 words; lane sl covers feats 4sl..4sl+3; one gather = 2 edges (one per half)
    const unsigned* hp8 = f8 + (size_t)((unsigned)(g * PP)) * 32 + sl;
    for (int p = 0; p < 4; p++) {                // per pass: half-wave handles nodes va, va+1
        int va = node0 + wv * 16 + p * 4 + half * 2;
        int vb = va + 1;
        int oa = offs[va], ca = degd[va];        // counts % 4 == 0
        int ob = offs[vb], cb = degd[vb];
        float A0 = 0.f, A1 = 0.f, A2 = 0.f, A3 = 0.f;
        float B0 = 0.f, B1 = 0.f, B2 = 0.f, B3 = 0.f;
        int c0 = ca < cb ? ca : cb;
        int cm = ca < cb ? cb : ca;
        int i = 0;
        for (; i < c0; i += 4) {                 // dual-node: 8 gathers in flight
            uint4 ra = *(const uint4*)(csr2 + oa + i);
            uint4 rb = *(const uint4*)(csr2 + ob + i);
            unsigned qa0 = hp8[(ra.x & 4095) * 32];
            unsigned qa1 = hp8[(ra.y & 4095) * 32];
            unsigned qa2 = hp8[(ra.z & 4095) * 32];
            unsigned qa3 = hp8[(ra.w & 4095) * 32];
            unsigned qb0 = hp8[(rb.x & 4095) * 32];
            unsigned qb1 = hp8[(rb.y & 4095) * 32];
            unsigned qb2 = hp8[(rb.z & 4095) * 32];
            unsigned qb3 = hp8[(rb.w & 4095) * 32];
            {
                f32x2 lo = __builtin_amdgcn_cvt_pk_f32_fp8((int)qa0, false);
                f32x2 hi = __builtin_amdgcn_cvt_pk_f32_fp8((int)qa0, true);
                float w = w16(ra.x);
                A0 += w * lo.x; A1 += w * lo.y; A2 += w * hi.x; A3 += w * hi.y;
            }
            {
                f32x2 lo = __builtin_amdgcn_cvt_pk_f32_fp8((int)qa1, false);
                f32x2 hi = __builtin_amdgcn_cvt_pk_f32_fp8((int)qa1, true);
                float w = w16(ra.y);
                A0 += w * lo.x; A1 += w * lo.y; A2 += w * hi.x; A3 += w * hi.y;
            }
            {
                f32x2 lo = __builtin_amdgcn_cvt_pk_f32_fp8((int)qa2, false);
                f32x2 hi = __builtin_amdgcn_cvt_pk_f32_fp8((int)qa2, true);
                float w = w16(ra.z);
                A0 += w * lo.x; A1 += w * lo.y; A2 += w * hi.x; A3 += w * hi.y;
            }
            {
                f32x2 lo = __builtin_amdgcn_cvt_pk_f32_fp8((int)qa3, false);
                f32x2 hi = __builtin_amdgcn_cvt_pk_f32_fp8((int)qa3, true);
                float w = w16(ra.w);
                A0 += w * lo.x; A1 += w * lo.y; A2 += w * hi.x; A3 += w * hi.y;
            }
            {
                f32x2 lo = __builtin_amdgcn_cvt_pk_f32_fp8((int)qb0, false);
                f32x2 hi = __builtin_amdgcn_cvt_pk_f32_fp8((int)qb0, true);
                float w = w16(rb.x);
                B0 += w * lo.x; B1 += w * lo.y; B2 += w * hi.x; B3 += w * hi.y;
            }
            {
                f32x2 lo = __builtin_amdgcn_cvt_pk_f32_fp8((int)qb1, false);
                f32x2 hi = __builtin_amdgcn_cvt_pk_f32_fp8((int)qb1, true);
                float w = w16(rb.y);
                B0 += w * lo.x; B1 += w * lo.y; B2 += w * hi.x; B3 += w * hi.y;
            }
            {
                f32x2 lo = __builtin_amdgcn_cvt_pk_f32_fp8((int)qb2, false);
                f32x2 hi = __builtin_amdgcn_cvt_pk_f32_fp8((int)qb2, true);
                float w = w16(rb.z);
                B0 += w * lo.x; B1 += w * lo.y; B2 += w * hi.x; B3 += w * hi.y;
            }
            {
                f32x2 lo = __builtin_amdgcn_cvt_pk_f32_fp8((int)qb3, false);
                f32x2 hi = __builtin_amdgcn_cvt_pk_f32_fp8((int)qb3, true);
                float w = w16(rb.w);
                B0 += w * lo.x; B1 += w * lo.y; B2 += w * hi.x; B3 += w * hi.y;
            }
        }
        if (i < cm) {                            // remainder: one node (per half) has extra
            int ot = (ca > cb) ? oa : ob;
            float E0 = 0.f, E1 = 0.f, E2 = 0.f, E3 = 0.f;
            for (; i < cm; i += 4) {
                uint4 rr = *(const uint4*)(csr2 + ot + i);
                unsigned q0 = hp8[(rr.x & 4095) * 32];
                unsigned q1 = hp8[(rr.y & 4095) * 32];
                unsigned q2 = hp8[(rr.z & 4095) * 32];
                unsigned q3 = hp8[(rr.w & 4095) * 32];
                {
                    f32x2 lo = __builtin_amdgcn_cvt_pk_f32_fp8((int)q0, false);
                    f32x2 hi = __builtin_amdgcn_cvt_pk_f32_fp8((int)q0, true);
                    float w = w16(rr.x);
                    E0 += w * lo.x; E1 += w * lo.y; E2 += w * hi.x; E3 += w * hi.y;
                }
                {
                    f32x2 lo = __builtin_amdgcn_cvt_pk_f32_fp8((int)q1, false);
                    f32x2 hi = __builtin_amdgcn_cvt_pk_f32_fp8((int)q1, true);
                    float w = w16(rr.y);
                    E0 += w * lo.x; E1 += w * lo.y; E2 += w * hi.x; E3 += w * hi.y;
                }
                {
                    f32x2 lo = __builtin_amdgcn_cvt_pk_f32_fp8((int)q2, false);
                    f32x2 hi = __builtin_amdgcn_cvt_pk_f32_fp8((int)q2, true);
                    float w = w16(rr.z);
                    E0 += w * lo.x; E1 += w * lo.y; E2 += w * hi.x; E3 += w * hi.y;
                }
                {
                    f32x2 lo = __builtin_amdgcn_cvt_pk_f32_fp8((int)q3, false);
                    f32x2 hi = __builtin_amdgcn_cvt_pk_f32_fp8((int)q3, true);
                    float w = w16(rr.w);
                    E0 += w * lo.x; E1 += w * lo.y; E2 += w * hi.x; E3 += w * hi.y;
                }
            }
            if (ca > cb) { A0 += E0; A1 += E1; A2 += E2; A3 += E3; }
            else         { B0 += E0; B1 += E1; B2 += E2; B3 += E3; }
        }
        float rda = rsd[va], rdb = rsd[vb];
        int lrA = wv * 16 + p * 4 + half * 2;
        *(uint2*)&lds[lrA * WP + sl * 2] =
            make_uint2(pack2bf(A0 * rda, A1 * rda), pack2bf(A2 * rda, A3 * rda));
        *(uint2*)&lds[(lrA + 1) * WP + sl * 2] =
            make_uint2(pack2bf(B0 * rdb, B1 * rdb), pack2bf(B2 * rdb, B3 * rdb));
    }
    __syncthreads();
    // MFMA: wave wv -> local rows wv*16..+15, K=128
    int m = lane & 15, quad = lane >> 4;
    bf16x8 a[4];
#pragma unroll
    for (int kt = 0; kt < 4; kt++)
        a[kt] = *(const bf16x8*)&lds[(wv * 16 + m) * WP + kt * 16 + quad * 4];
#pragma unroll
    for (int nt = 0; nt < 8; nt++) {
        f32x4 acc = {0.f, 0.f, 0.f, 0.f};
#pragma unroll
        for (int kt = 0; kt < 4; kt++) {
            bf16x8 b = *(const bf16x8*)(PW + ((size_t)(kt * 8 + nt) * 64 + lane) * 8);
            acc = __builtin_amdgcn_mfma_f32_16x16x32_bf16(a[kt], b, acc, 0, 0, 0);
        }
        int col = nt * 16 + m;
        int r0 = node0 + wv * 16 + quad * 4;
        float ps = 0.f, pq = 0.f;
#pragma unroll
        for (int r = 0; r < 4; r++) {
            C[(size_t)(r0 + r) * HH + col] = (unsigned short)f2bf(acc[r]);
            ps += acc[r]; pq += acc[r] * acc[r];
        }
        atomicAdd(&s1[col], ps);
        atomicAdd(&s2[col], pq);
    }
    __syncthreads();
    if (t < HH) {
        part[bid * 256 + t]      = s1[t];
        part[bid * 256 + HH + t] = s2[t];
    }
}

// ---------------- stage-1 reduction of gemm partials ----------------
__global__ __launch_bounds__(256) void k_red(const float* __restrict__ part,
                                             float* __restrict__ pb) {
    int t = threadIdx.x, b = blockIdx.x;        // 64 blocks
    float s = 0.f;
    for (int r = 0; r < 32; r++) s += part[(size_t)(b * 32 + r) * 256 + t];
    pb[b * 256 + t] = s;
}

// ---------------- reduce + norm coefficients ----------------
__global__ void k_coef(const float* __restrict__ pb, const float* __restrict__ gamma,
                       const float* __restrict__ beta, const float* __restrict__ alpha,
                       float* __restrict__ ab) {
    int t = threadIdx.x;                         // 256 threads
    float s = 0.f;
    for (int b = 0; b < 64; b++) s += pb[b * 256 + t];
    __shared__ float sh[256];
    sh[t] = s;
    __syncthreads();
    if (t < 128) {
        float mu = sh[t] * (1.f / NN);
        float e2 = sh[128 + t] * (1.f / NN);
        float al = alpha[t];
        float var = e2 - (2.f * al - al * al) * mu * mu;
        float a = rsqrtf(var + EPSV) * gamma[t];
        ab[t] = a;
        ab[HH + t] = beta[t] - al * mu * a;
    }
}

// ---------------- fused norm + leaky-relu (+fp8 h1 emit) + per-graph readout ----------------
template <bool WRITE>
__global__ __launch_bounds__(256) void k_normro(const unsigned* __restrict__ h,  // bf16 pairs
                                                const float* __restrict__ ab,
                                                float* __restrict__ racc,
                                                unsigned short* __restrict__ f8) {
    int fp = threadIdx.x & 63;                   // feature pair
    int q  = threadIdx.x >> 6;                   // 0..3
    int node0 = blockIdx.x * 64;                 // one graph per block
    int g = node0 / PP;
    float a0 = ab[2 * fp], a1 = ab[2 * fp + 1];
    float b0 = ab[HH + 2 * fp], b1 = ab[HH + 2 * fp + 1];
    float s0 = 0.f, s1 = 0.f;
    for (int i = q; i < 64; i += 4) {
        size_t idx = (size_t)(node0 + i) * 64 + fp;
        unsigned v = h[idx];
        float x0 = fmaf(a0, bflo(v), b0); x0 = x0 > 0.f ? x0 : SLOPEV * x0;
        float x1 = fmaf(a1, bfhi(v), b1); x1 = x1 > 0.f ? x1 : SLOPEV * x1;
        if (WRITE) f8[idx] = (unsigned short)__builtin_amdgcn_cvt_pk_fp8_f32(x0, x1, 0, false);
        s0 += x0; s1 += x1;
    }
    __shared__ float sh[512];
    sh[threadIdx.x] = s0;
    sh[256 + threadIdx.x] = s1;
    __syncthreads();
    if (q == 0) {
        float t0 = s0 + sh[64 + fp] + sh[128 + fp] + sh[192 + fp];
        float t1 = s1 + sh[256 + 64 + fp] + sh[256 + 128 + fp] + sh[256 + 192 + fp];
        atomicAdd(&racc[g * HH + 2 * fp],     t0);
        atomicAdd(&racc[g * HH + 2 * fp + 1], t1);
    }
}

// ---------------- final head ----------------
__global__ void k_final(const float* __restrict__ racc1, const float* __restrict__ racc2,
                        const float* __restrict__ Wc, float* __restrict__ out) {
    int t = threadIdx.x;                         // 512 = 32*16
    int b = t >> 4, o = t & 15;
    float acc = 0.f;
    for (int f = 0; f < HH; f++) acc += racc1[b * HH + f] * Wc[o * (2 * HH) + f];
    for (int f = 0; f < HH; f++) acc += racc2[b * HH + f] * Wc[o * (2 * HH) + HH + f];
    out[t] = acc * (1.f / PP);
}

extern "C" void kernel_launch(void* const* d_in, const int* in_sizes, int n_in,
                              void* d_out, int out_size, void* d_ws, size_t ws_size,
                              hipStream_t stream) {
    const float* features = (const float*)d_in[0];
    const float* ew       = (const float*)d_in[1];
    const int*   src      = (const int*)d_in[2];
    const int*   dst      = (const int*)d_in[3];
    const float* W1       = (const float*)d_in[4];
    const float* W2       = (const float*)d_in[5];
    const float* Wc       = (const float*)d_in[6];
    const float* gamma1   = (const float*)d_in[7];
    const float* beta1    = (const float*)d_in[8];
    const float* alpha1   = (const float*)d_in[9];
    const float* gamma2   = (const float*)d_in[10];
    const float* beta2    = (const float*)d_in[11];
    const float* alpha2   = (const float*)d_in[12];
    float* out = (float*)d_out;

    char* w = (char*)d_ws;
    // misc block [0, 1 MB)
    int*    gcur   = (int*)(w + 0);                         // 32 * 16 ints
    float*  racc1  = (float*)(w + (16u << 10));             // 16 KB
    float*  racc2  = (float*)(w + (32u << 10));             // contiguous with racc1
    float*  ab1    = (float*)(w + (48u << 10));
    float*  ab2    = (float*)(w + (52u << 10));
    unsigned short* pw1 = (unsigned short*)(w + (64u << 10));   // 16 KB
    unsigned short* pw2 = (unsigned short*)(w + (80u << 10));   // 32 KB
    float*  pb     = (float*)(w + (128u << 10));            // 64 KB
    // arrays
    float*  rs_s   = (float*)(w + (1024u << 10));           // 512 KB
    float*  rsd    = (float*)(w + (1536u << 10));           // 512 KB
    int*    degd   = (int*)(w + (2048u << 10));             // 512 KB
    int*    offs   = (int*)(w + (2560u << 10));             // 512 KB
    float*  part   = (float*)(w + (3u << 20));              // 2 MB: 3..5
    int*    shist  = (int*)(w + (5u << 20));                // 4 MB: 5..9
    int*    dhist  = (int*)(w + (9u << 20));                // 4 MB: 9..13
    unsigned* csr2 = (unsigned*)(w + (13u << 20));          // 10 MB: 13..23
    unsigned* mbuf = (unsigned*)(w + (23u << 20));          // 32 MB: 23..55 (h2pre)
    unsigned* hbuf = (unsigned*)(w + (55u << 20));          // 32 MB: 55..87 (h1pre)
    uint2*    recs = (uint2*)(w + (87u << 20));             // 20 MB: 87..107
    unsigned* f8x  = (unsigned*)(w + (107u << 20));         // 8 MB: 107..115 (features fp8)
    unsigned* f8buf= (unsigned*)(w + (123u << 20));         // 16 MB: 123..139 (h1 fp8)

    // prep (feature->fp8 + init + packw + csr2 zero, fused)
    k_prep<<<10765, 256, 0, stream>>>(features, f8x, W1, pw1, W2, pw2, gcur, racc1, csr2);

    // CSR build
    k_part<<<EE / 4096, 256, 0, stream>>>(src, dst, ew, gcur, recs);
    k_hist<<<BG * 8, 1024, 0, stream>>>(recs, gcur, shist, dhist);
    k_offs<<<BG, 1024, 0, stream>>>(shist, dhist, rs_s, rsd, degd, offs);
    k_place<<<BG * 8, 1024, 0, stream>>>(recs, gcur, dhist, rs_s, csr2);

    // ---- layer 1 (fused agg+gemm; gathers fp8 features) ----
    k_aggemm1<<<NN / 64, 256, 0, stream>>>(f8x, csr2, offs, degd, rsd,
                                           (const short*)pw1, (unsigned short*)hbuf, part);
    k_red<<<64, 256, 0, stream>>>(part, pb);
    k_coef<<<1, 256, 0, stream>>>(pb, gamma1, beta1, alpha1, ab1);
    k_normro<true><<<NN / 64, 256, 0, stream>>>(hbuf, ab1, racc1, (unsigned short*)f8buf);

    // ---- layer 2 (fused agg+gemm; gathers fp8 h1, writes mbuf) ----
    k_aggemm2<<<NN / 64, 256, 0, stream>>>(f8buf, csr2, offs, degd, rsd,
                                           (const short*)pw2, (unsigned short*)mbuf, part);
    k_red<<<64, 256, 0, stream>>>(part, pb);
    k_coef<<<1, 256, 0, stream>>>(pb, gamma2, beta2, alpha2, ab2);
    k_normro<false><<<NN / 64, 256, 0, stream>>>(mbuf, ab2, racc2, nullptr);

    // ---- head ----
    k_final<<<1, 512, 0, stream>>>(racc1, racc2, Wc, out);
}